// Round 7
// baseline (393.186 us; speedup 1.0000x reference)
//
#include <hip/hip_runtime.h>
#include <hip/hip_bf16.h>

typedef __bf16 bf16x8 __attribute__((ext_vector_type(8)));
typedef float  f32x4  __attribute__((ext_vector_type(4)));
typedef short  short4v __attribute__((ext_vector_type(4)));

#define B_SZ   2
#define T_SEQ  2048
#define C_EMB  2048
#define NH     16
#define HD     128
#define M_ROWS (B_SZ * T_SEQ)   /* 4096 */
#define N_QKV  (3 * C_EMB)      /* 6144 */
#define LQK    (2 * C_EMB)      /* 4096: qk buffer row length (q|k columns) */

// Global K layout (qk cols [2048,4096)): within-head col c stored at
//   c ^ ((t&7)<<3)   (t = key row). Global V^T layout (vt): within each
// 64-key tile, key col t stored at t ^ ((d&7)<<3) (d = vt row & 127).
// Both swizzles let attn stage tiles LINEARLY via global_load_lds and read
// conflict-free with the same XOR (both-sides involution).

static __device__ __forceinline__ unsigned short f2b(float f) {
  union { __hip_bfloat16 h; unsigned short u; } cv;
  cv.h = __float2bfloat16(f);
  return cv.u;
}
static __device__ __forceinline__ void store_out(float* p, float v) { *p = v; }
static __device__ __forceinline__ void store_out(unsigned short* p, float v) { *p = f2b(v); }

static __device__ __forceinline__ ushort4 load4_bf16(const float* p) {
  float4 v = *(const float4*)p;
  ushort4 o; o.x = f2b(v.x); o.y = f2b(v.y); o.z = f2b(v.z); o.w = f2b(v.w);
  return o;
}
static __device__ __forceinline__ ushort4 load4_bf16(const unsigned short* p) {
  return *(const ushort4*)p;
}

// async global->LDS, 16B/lane; LDS dest must be wave-uniform base + lane*16
static __device__ __forceinline__ void async_cp16(const unsigned short* g, unsigned short* l) {
  __builtin_amdgcn_global_load_lds((__attribute__((address_space(1))) void*)(g),
                                   (__attribute__((address_space(3))) void*)(l), 16, 0, 0);
}

// ---------------------------------------------------------------------------
// Shared epilogue. MODE 0: C = acc + bias. MODE 1 (qkv split): q cols linear;
// k cols swizzled within head; v cols -> vt transposed+swizzled.
// ---------------------------------------------------------------------------
template <int MODE, typename OutT>
static __device__ __forceinline__ void gemm_epilogue(
    f32x4 (&acc)[4][4], const float* __restrict__ bias,
    OutT* __restrict__ C, int ldc,
    unsigned short* __restrict__ qk, unsigned short* __restrict__ vt,
    int bm0, int bn0, int wm, int wn, int ln, int lq) {
  #pragma unroll
  for (int i = 0; i < 4; ++i) {
    const int row0 = bm0 + wm * 64 + i * 16 + lq * 4;
    #pragma unroll
    for (int j = 0; j < 4; ++j) {
      const int col = bn0 + wn * 64 + j * 16 + ln;
      const float bv = bias[col];
      if constexpr (MODE == 0) {
        #pragma unroll
        for (int r = 0; r < 4; ++r)
          store_out(&C[(size_t)(row0 + r) * ldc + col], acc[i][j][r] + bv);
      } else {
        if (bn0 < C_EMB) {              // q columns: linear
          #pragma unroll
          for (int r = 0; r < 4; ++r)
            qk[(size_t)(row0 + r) * LQK + col] = f2b(acc[i][j][r] + bv);
        } else if (bn0 < 2 * C_EMB) {   // k columns: swizzled within head
          #pragma unroll
          for (int r = 0; r < 4; ++r) {
            const int row = row0 + r;
            qk[(size_t)row * LQK + (col & ~127) + ((col & 127) ^ ((row & 7) << 3))] =
                f2b(acc[i][j][r] + bv);
          }
        } else {                        // v columns -> transposed+swizzled store
          const int c2 = col - 2 * C_EMB;           // h*128 + d
          const int bb = row0 >> 11;                // batch
          const int t0 = row0 & (T_SEQ - 1);
          const int vrow = (bb * NH + (c2 >> 7)) * HD + (c2 & 127);
          ushort4 p;
          p.x = f2b(acc[i][j][0] + bv); p.y = f2b(acc[i][j][1] + bv);
          p.z = f2b(acc[i][j][2] + bv); p.w = f2b(acc[i][j][3] + bv);
          *(ushort4*)(vt + (size_t)vrow * T_SEQ + (t0 ^ ((vrow & 7) << 3))) = p;  // stays in 64-tile
        }
      }
    }
  }
}

// ---------------------------------------------------------------------------
// Tier A 128-tile GEMM (m97 structure) — retained for the proj GEMM.
// ---------------------------------------------------------------------------
template <int MODE, typename OutT>
__global__ __launch_bounds__(256) void gemm_bt(const unsigned short* __restrict__ A, int lda,
                                               const unsigned short* __restrict__ Bt,
                                               const float* __restrict__ bias,
                                               OutT* __restrict__ C, int ldc,
                                               unsigned short* __restrict__ qk,
                                               unsigned short* __restrict__ vt,
                                               int N, int K) {
  __shared__ __align__(16) unsigned short As[128 * 32];
  __shared__ __align__(16) unsigned short Bs[128 * 32];
  const int tid = threadIdx.x;
  const int wave = tid >> 6, lane = tid & 63;
  const int wm = wave >> 1, wn = wave & 1;
  const int ln = lane & 15, lq = lane >> 4;
  const int bm0 = blockIdx.y * 128, bn0 = blockIdx.x * 128;

  f32x4 acc[4][4];
  #pragma unroll
  for (int i = 0; i < 4; ++i)
    #pragma unroll
    for (int j = 0; j < 4; ++j) acc[i][j] = (f32x4){0.f, 0.f, 0.f, 0.f};

  const unsigned short* Ag = A  + (size_t)(bm0 + wave * 32 + (lane >> 2)) * lda + (lane & 3) * 8;
  const unsigned short* Bg = Bt + (size_t)(bn0 + wave * 32 + (lane >> 2)) * K   + (lane & 3) * 8;
  unsigned short* Al = As + wave * 1024 + lane * 8;
  unsigned short* Bl = Bs + wave * 1024 + lane * 8;

  for (int k0 = 0; k0 < K; k0 += 32) {
    async_cp16(Ag + k0, Al);
    async_cp16(Ag + k0 + 16 * lda, Al + 512);
    async_cp16(Bg + k0, Bl);
    async_cp16(Bg + k0 + 16 * K, Bl + 512);
    __syncthreads();
    bf16x8 af[4], bfv[4];
    #pragma unroll
    for (int i = 0; i < 4; ++i) {
      af[i]  = *(const bf16x8*)(As + (wm * 64 + i * 16 + ln) * 32 + lq * 8);
      bfv[i] = *(const bf16x8*)(Bs + (wn * 64 + i * 16 + ln) * 32 + lq * 8);
    }
    #pragma unroll
    for (int i = 0; i < 4; ++i)
      #pragma unroll
      for (int j = 0; j < 4; ++j)
        acc[i][j] = __builtin_amdgcn_mfma_f32_16x16x32_bf16(af[i], bfv[j], acc[i][j], 0, 0, 0);
    __syncthreads();
  }
  gemm_epilogue<MODE, OutT>(acc, bias, C, ldc, qk, vt, bm0, bn0, wm, wn, ln, lq);
}

// ---------------------------------------------------------------------------
// 256x256 8-phase GEMM (r5 version — best measured at 125.0 µs; r6's 128x256
// retile regressed: worse LDS:MFMA ratio. Schedule = r1's; no sched_barrier).
//   Staging: ph1 A(t1,h0), ph2 A(t1,h1), ph3 B(ta,h0), ph4 B(ta,h1)+VMC4;
//   symmetric ph5-ph8. VMC4 at ph4: queue = [B(t1)4, A(t1)4, B(ta)4] ->
//   drains A(t1) (buf1 complete). At ph8: drains A(ta) (buf0 for next ph1).
//   Tail iteration re-stages current tiles (identical bytes -> benign).
// ---------------------------------------------------------------------------
#define BAR8 __builtin_amdgcn_s_barrier()
#define VMC4 asm volatile("s_waitcnt vmcnt(4)" ::: "memory")

#define STAGE_A8(t, h) do { \
    const unsigned short* g_ = Ag0 + (size_t)((h) * 128) * lda + (t) * 64; \
    unsigned short* l_ = ldsA + ((t) & 1) * 16384 + (h) * 8192 + tid * 8; \
    async_cp16(g_, l_); \
    async_cp16(g_ + (size_t)64 * lda, l_ + 4096); \
  } while (0)
#define STAGE_B8(t, h) do { \
    const unsigned short* g_ = Bg0 + (size_t)((h) * 128) * ldb + (t) * 64; \
    unsigned short* l_ = ldsB + ((t) & 1) * 16384 + (h) * 8192 + tid * 8; \
    async_cp16(g_, l_); \
    async_cp16(g_ + (size_t)64 * ldb, l_ + 4096); \
  } while (0)

#define LOADA8(ab, rq) do { \
    _Pragma("unroll") for (int rt_ = 0; rt_ < 4; ++rt_) { \
      af[rt_][0] = *(const bf16x8*)((ab) + (rq) * 4096 + rt_ * 1024 + kx0); \
      af[rt_][1] = *(const bf16x8*)((ab) + (rq) * 4096 + rt_ * 1024 + kx1); \
    } } while (0)
#define LOADB8(bb, cj0) do { \
    bv_[(cj0)][0]     = *(const bf16x8*)((bb) + (cj0) * 1024 + kx0); \
    bv_[(cj0)][1]     = *(const bf16x8*)((bb) + (cj0) * 1024 + kx1); \
    bv_[(cj0) + 1][0] = *(const bf16x8*)((bb) + ((cj0) + 1) * 1024 + kx0); \
    bv_[(cj0) + 1][1] = *(const bf16x8*)((bb) + ((cj0) + 1) * 1024 + kx1); \
  } while (0)
#define MFMAQ8(rq, cq) do { \
    __builtin_amdgcn_s_setprio(1); \
    _Pragma("unroll") for (int rt_ = 0; rt_ < 4; ++rt_) \
      _Pragma("unroll") for (int ct_ = 0; ct_ < 2; ++ct_) \
        _Pragma("unroll") for (int kk_ = 0; kk_ < 2; ++kk_) \
          acc[(rq) * 4 + rt_][(cq) * 2 + ct_] = __builtin_amdgcn_mfma_f32_16x16x32_bf16( \
              af[rt_][kk_], bv_[(cq) * 2 + ct_][kk_], acc[(rq) * 4 + rt_][(cq) * 2 + ct_], 0, 0, 0); \
    __builtin_amdgcn_s_setprio(0); \
  } while (0)

template <int MODE, typename OutT>
__global__ __launch_bounds__(512, 2) void gemm8_bt(
    const unsigned short* __restrict__ A, int lda,
    const unsigned short* __restrict__ Bt, int ldb,
    const float* __restrict__ bias,
    OutT* __restrict__ C, int ldc,
    unsigned short* __restrict__ qk, unsigned short* __restrict__ vt, int K) {
  __shared__ __align__(16) unsigned short lds8[65536];  // 128 KiB
  unsigned short* ldsA = lds8;
  unsigned short* ldsB = lds8 + 32768;

  const int tid = threadIdx.x;
  const int wave = tid >> 6, lane = tid & 63;
  const int wm = wave >> 2, wn = wave & 3;
  const int ln = lane & 15, lq = lane >> 4;

  const int nbx = gridDim.x;
  int bid = blockIdx.y * nbx + blockIdx.x;
  const int nwg = nbx * gridDim.y;
  if (!(nwg & 7)) bid = (bid & 7) * (nwg >> 3) + (bid >> 3);   // XCD swizzle (bijective: nwg%8==0)
  const int bm0 = (bid / nbx) * 256;
  const int bn0 = (bid % nbx) * 256;

  // staging addressing: thread covers rows (tid>>3) and (tid>>3)+64 of a half,
  // 16B slot (tid&7); pre-swizzled global k-offset = (slot ^ (row&7))*8 shorts.
  const int srow = tid >> 3;
  const int scol = ((tid & 7) ^ (srow & 7)) << 3;
  const unsigned short* Ag0 = A  + (size_t)(bm0 + srow) * lda + scol;
  const unsigned short* Bg0 = Bt + (size_t)(bn0 + srow) * ldb + scol;

  // compute-side swizzled k-offsets (shorts): (ko + lq*8) ^ ((ln&7)<<3)
  const int kx0 = (lq * 8) ^ ((ln & 7) << 3);
  const int kx1 = (32 + lq * 8) ^ ((ln & 7) << 3);
  const unsigned short* Ab0 = lds8 + wm * 8192 + ln * 64;
  const unsigned short* Bb0 = lds8 + 32768 + (wn >> 1) * 8192 + ((wn & 1) * 64 + ln) * 64;
  const unsigned short* Ab1 = Ab0 + 16384;
  const unsigned short* Bb1 = Bb0 + 16384;

  f32x4 acc[8][4];
  #pragma unroll
  for (int i = 0; i < 8; ++i)
    #pragma unroll
    for (int j = 0; j < 4; ++j) acc[i][j] = (f32x4){0.f, 0.f, 0.f, 0.f};
  bf16x8 af[4][2], bv_[4][2];

  // prologue: tile0 fully + tile1's B halves (A(t1) staged at ph1/ph2).
  // 12 issued, VMC4 -> tile0's 8 landed; in flight B(t1)x4 (matches ph1 entry).
  STAGE_A8(0, 0); STAGE_A8(0, 1); STAGE_B8(0, 0); STAGE_B8(0, 1);
  STAGE_B8(1, 0); STAGE_B8(1, 1);
  VMC4;
  BAR8;

  const int NT = K >> 6, NI = NT >> 1;
  for (int i = 0; i < NI; ++i) {
    const int t1 = 2 * i + 1;
    const int ta = (2 * i + 2 < NT) ? (2 * i + 2) : (2 * i);      // tail: restage (same bytes)
    const int tb = (2 * i + 3 < NT) ? (2 * i + 3) : (2 * i + 1);
    // ---- K-tile t0 (buf0)
    LOADA8(Ab0, 0); LOADB8(Bb0, 0); STAGE_A8(t1, 0);        BAR8; MFMAQ8(0, 0); BAR8;  // ph1
    LOADB8(Bb0, 2);                 STAGE_A8(t1, 1);        BAR8; MFMAQ8(0, 1); BAR8;  // ph2
    LOADA8(Ab0, 1);                 STAGE_B8(ta, 0);        BAR8; MFMAQ8(1, 0); BAR8;  // ph3
                                    STAGE_B8(ta, 1); VMC4;  BAR8; MFMAQ8(1, 1); BAR8;  // ph4
    // ---- K-tile t1 (buf1)
    LOADA8(Ab1, 0); LOADB8(Bb1, 0); STAGE_A8(ta, 0);        BAR8; MFMAQ8(0, 0); BAR8;  // ph5
    LOADB8(Bb1, 2);                 STAGE_A8(ta, 1);        BAR8; MFMAQ8(0, 1); BAR8;  // ph6
    LOADA8(Ab1, 1);                 STAGE_B8(tb, 0);        BAR8; MFMAQ8(1, 0); BAR8;  // ph7
                                    STAGE_B8(tb, 1); VMC4;  BAR8; MFMAQ8(1, 1); BAR8;  // ph8
  }

  // ---- epilogue: wave rows bm0+wm*128+ri*16+lq*4+r, cols bn0+wn*64+cj*16+ln
  #pragma unroll
  for (int ri = 0; ri < 8; ++ri) {
    const int row0 = bm0 + wm * 128 + ri * 16 + lq * 4;
    #pragma unroll
    for (int cj = 0; cj < 4; ++cj) {
      const int col = bn0 + wn * 64 + cj * 16 + ln;
      const float bvs = bias[col];
      if constexpr (MODE == 0) {
        #pragma unroll
        for (int r = 0; r < 4; ++r)
          store_out(&C[(size_t)(row0 + r) * ldc + col], acc[ri][cj][r] + bvs);
      } else {
        if (bn0 < C_EMB) {              // q cols: linear (256-tile never straddles)
          #pragma unroll
          for (int r = 0; r < 4; ++r)
            qk[(size_t)(row0 + r) * LQK + col] = f2b(acc[ri][cj][r] + bvs);
        } else if (bn0 < 2 * C_EMB) {   // k cols: swizzled within head
          #pragma unroll
          for (int r = 0; r < 4; ++r) {
            const int row = row0 + r;
            qk[(size_t)row * LQK + (col & ~127) + ((col & 127) ^ ((row & 7) << 3))] =
                f2b(acc[ri][cj][r] + bvs);
          }
        } else {                        // v cols -> transposed+swizzled store into vt
          const int c2 = col - 2 * C_EMB;
          const int bb = row0 >> 11;
          const int t0v = row0 & (T_SEQ - 1);
          const int vrow = (bb * NH + (c2 >> 7)) * HD + (c2 & 127);
          ushort4 p;
          p.x = f2b(acc[ri][cj][0] + bvs); p.y = f2b(acc[ri][cj][1] + bvs);
          p.z = f2b(acc[ri][cj][2] + bvs); p.w = f2b(acc[ri][cj][3] + bvs);
          *(ushort4*)(vt + (size_t)vrow * T_SEQ + (t0v ^ ((vrow & 7) << 3))) = p;
        }
      }
    }
  }
}

// ---------------------------------------------------------------------------
// Tier B GEMM fallback (validated round-2 structure).
// ---------------------------------------------------------------------------
template <int MODE, typename AT, typename OutT>
__global__ __launch_bounds__(256) void gemm_any(const AT* __restrict__ A, int lda,
                                                const float* __restrict__ B, int ldb,
                                                const float* __restrict__ bias,
                                                OutT* __restrict__ C, int ldc,
                                                unsigned short* __restrict__ qk,
                                                unsigned short* __restrict__ vt,
                                                int N, int K) {
  __shared__ __align__(16) unsigned short As[128 * 32];
  __shared__ __align__(16) unsigned short Bs[128 * 32];
  __shared__ __align__(16) float Bstage[32 * 132];

  const int tid = threadIdx.x;
  const int wave = tid >> 6, lane = tid & 63;
  const int wm = wave >> 1, wn = wave & 1;
  const int ln = lane & 15, lq = lane >> 4;
  const int bm0 = blockIdx.y * 128, bn0 = blockIdx.x * 128;

  f32x4 acc[4][4];
  #pragma unroll
  for (int i = 0; i < 4; ++i)
    #pragma unroll
    for (int j = 0; j < 4; ++j) acc[i][j] = (f32x4){0.f, 0.f, 0.f, 0.f};

  for (int k0 = 0; k0 < K; k0 += 32) {
    #pragma unroll
    for (int j = 0; j < 4; ++j) {
      const int item = tid + j * 256;
      const int m = item >> 3;
      const int kf = (item & 7) * 4;
      *(ushort4*)(As + m * 32 + kf) = load4_bf16(A + (size_t)(bm0 + m) * lda + k0 + kf);
    }
    #pragma unroll
    for (int j = 0; j < 4; ++j) {
      const int item = tid + j * 256;
      const int kr = item >> 5;
      const int nf = (item & 31) * 4;
      *(float4*)(Bstage + kr * 132 + nf) =
          *(const float4*)(B + (size_t)(k0 + kr) * ldb + bn0 + nf);
    }
    __syncthreads();
    #pragma unroll
    for (int j = 0; j < 4; ++j) {
      const int item = tid + j * 256;
      const int n = item >> 3;
      const int kq = item & 7;
      const int k = kq * 4;
      ushort4 h4;
      h4.x = f2b(Bstage[(k + 0) * 132 + n]);
      h4.y = f2b(Bstage[(k + 1) * 132 + n]);
      h4.z = f2b(Bstage[(k + 2) * 132 + n]);
      h4.w = f2b(Bstage[(k + 3) * 132 + n]);
      *(ushort4*)(Bs + n * 32 + (((kq >> 1) ^ (n & 3)) << 3) + ((kq & 1) << 2)) = h4;
    }
    __syncthreads();
    bf16x8 af[4], bfv[4];
    #pragma unroll
    for (int i = 0; i < 4; ++i) {
      af[i] = *(const bf16x8*)(As + (wm * 64 + i * 16 + ln) * 32 + lq * 8);
      const int n = wn * 64 + i * 16 + ln;
      bfv[i] = *(const bf16x8*)(Bs + n * 32 + ((lq ^ (n & 3)) << 3));
    }
    #pragma unroll
    for (int i = 0; i < 4; ++i)
      #pragma unroll
      for (int j = 0; j < 4; ++j)
        acc[i][j] = __builtin_amdgcn_mfma_f32_16x16x32_bf16(af[i], bfv[j], acc[i][j], 0, 0, 0);
    __syncthreads();
  }
  gemm_epilogue<MODE, OutT>(acc, bias, C, ldc, qk, vt, bm0, bn0, wm, wn, ln, lq);
}

// --------------------------------------------------------------- prep (fused)
static __device__ __forceinline__ void transpose_body(
    const float* __restrict__ in, unsigned short* __restrict__ out,
    int R, int Cc, int bx, int by, float (*t)[33]) {
  const int tx = threadIdx.x & 31, ty = threadIdx.x >> 5;
  #pragma unroll
  for (int j = 0; j < 32; j += 8)
    t[ty + j][tx] = in[(size_t)(by + ty + j) * Cc + bx + tx];
  __syncthreads();
  #pragma unroll
  for (int j = 0; j < 32; j += 8)
    out[(size_t)(bx + ty + j) * R + by + tx] = f2b(t[tx][ty + j]);
}

__global__ __launch_bounds__(256) void prep_all(
    const float* __restrict__ x, unsigned short* __restrict__ xb,
    const float* __restrict__ Wa, unsigned short* __restrict__ WaT,
    const float* __restrict__ Wp, unsigned short* __restrict__ WpT) {
  __shared__ float t[32][33];
  const int NCAST = (M_ROWS * C_EMB / 4) / 256;        // 8192
  const int NTA_X = N_QKV / 32;                        // 192
  const int NTA   = NTA_X * (C_EMB / 32);              // 12288
  const int NTP_X = C_EMB / 32;                        // 64
  const int bid = blockIdx.x;
  if (bid < NCAST) {
    const int i = bid * 256 + threadIdx.x;
    float4 v = ((const float4*)x)[i];
    ushort4 o; o.x = f2b(v.x); o.y = f2b(v.y); o.z = f2b(v.z); o.w = f2b(v.w);
    ((ushort4*)xb)[i] = o;
  } else if (bid < NCAST + NTA) {
    const int tb = bid - NCAST;
    transpose_body(Wa, WaT, C_EMB, N_QKV, (tb % NTA_X) * 32, (tb / NTA_X) * 32, t);
  } else {
    const int tb = bid - NCAST - NTA;
    transpose_body(Wp, WpT, C_EMB, C_EMB, (tb % NTP_X) * 32, (tb / NTP_X) * 32, t);
  }
}

// ---------------------------------------------------------------------------
// Flash attention r7: 4-wave (256-thread) blocks, 32 queries per wave
// (2 x 16-query subtiles). Each K/V LDS byte read ONCE per wave now feeds
// BOTH subtiles' MFMAs -> LDS:MFMA ratio halves (attn was LDS-BW-bound:
// each wave previously read the full 32KB K+V tile for 0.52 MFLOP).
// Same proven skeleton: dbuf K/V via global_load_lds (swizzle baked into
// global layout), counted vmcnt(8), raw s_barrier, setprio, max-free softmax.
// Block = 128 q (4 waves x 32); grid (16, NH, B) = 512 blocks; LDS 64KiB ->
// 2 blocks/CU -> 1 full round on 256 CUs.
// Wave-active condition: kb*64 <= wq0+31; since kb*64 - wq0 is a multiple of
// 32, an active wave always has BOTH subtiles active (no wasted MFMA).
// ---------------------------------------------------------------------------
__global__ __launch_bounds__(256, 2) void attn_st(unsigned short* __restrict__ qk,
                                                  const unsigned short* __restrict__ vt) {
  // 2 buffers x (K [64][128] + V^T [128][64]) = 2 x 16384 shorts = 64 KiB.
  // Epilogue reuses [0..17408) as Os[128][136].
  __shared__ __align__(16) unsigned short smem[32768];

  const int tid = threadIdx.x;
  const int w = tid >> 6, lane = tid & 63;
  const int ln = lane & 15, lq = lane >> 4;
  const int b = blockIdx.z, h = blockIdx.y;
  const int j = (b == 0) ? (15 - (int)blockIdx.x) : (int)blockIdx.x;
  const int qb0 = j * 128;
  const float EXPSC = 0.08838834764831845f * 1.4426950408889634f;
  const int xsw = (ln & 7) << 3;   // read-side XOR (row&7 == ln&7 for K and V reads)

  const int wq0 = qb0 + w * 32;    // wave's 32 queries: [wq0, wq0+31]
  const int qg0 = wq0 + ln, qg1 = wq0 + 16 + ln;

  // Q fragments for both subtiles (B-operand: n=query, k=lq*8..)
  bf16x8 bq0[4], bq1[4];
  {
    const unsigned short* Qp0 = qk + (size_t)(b * T_SEQ + qg0) * LQK + h * HD + lq * 8;
    const unsigned short* Qp1 = qk + (size_t)(b * T_SEQ + qg1) * LQK + h * HD + lq * 8;
    #pragma unroll
    for (int ks = 0; ks < 4; ++ks) {
      bq0[ks] = *(const bf16x8*)(Qp0 + ks * 32);
      bq1[ks] = *(const bf16x8*)(Qp1 + ks * 32);
    }
  }

  // staging bases (global layouts pre-swizzled -> linear row copies)
  const unsigned short* Kg = qk + (size_t)(b * T_SEQ) * LQK + C_EMB + h * HD;
  const unsigned short* Vg = vt + ((size_t)(b * NH + h) * HD) * T_SEQ;

  // 256 threads stage a 16KB K tile + 16KB V tile: 8 cp16/thread.
  // K[row][128]: item s -> row s>>4, 16B slot s&15 -> LDS short off s*8.
  // V[row][64]:  item s -> row s>>3, 16B slot s&7  -> LDS short off 8192+s*8.
#define ATTN_STAGE(kn, dstbuf) do { \
    _Pragma("unroll") for (int jj_ = 0; jj_ < 4; ++jj_) { \
      const int s_ = tid + jj_ * 256; \
      async_cp16(Kg + (size_t)((kn) * 64 + (s_ >> 4)) * LQK + (s_ & 15) * 8, (dstbuf) + s_ * 8); \
    } \
    _Pragma("unroll") for (int jj_ = 0; jj_ < 4; ++jj_) { \
      const int s_ = tid + jj_ * 256; \
      async_cp16(Vg + (size_t)(s_ >> 3) * T_SEQ + (kn) * 64 + (s_ & 7) * 8, \
                 (dstbuf) + 8192 + s_ * 8); \
    } \
  } while (0)

  f32x4 ot0[8], ot1[8];  // O^T accum per subtile: reg r -> d = dt*16+lq*4+r, col = query ln
  #pragma unroll
  for (int dt = 0; dt < 8; ++dt) {
    ot0[dt] = (f32x4){0.f, 0.f, 0.f, 0.f};
    ot1[dt] = (f32x4){0.f, 0.f, 0.f, 0.f};
  }
  float l0 = 0.f, l1 = 0.f;

  // prologue: stage tiles 0 (buf0) and 1 (buf1): 8 cp16/thread each
  ATTN_STAGE(0, smem);
  ATTN_STAGE(1, smem + 16384);

  const int kbmax = 2 * j + 1;
  for (int kb = 0; kb <= kbmax; ++kb) {
    asm volatile("s_waitcnt vmcnt(8)" ::: "memory");  // tile kb landed (kb+1 in flight)
    __builtin_amdgcn_s_barrier();
    const unsigned short* Ksb = smem + (kb & 1) * 16384;
    const unsigned short* Vsb = Ksb + 8192;

    if (kb * 64 <= wq0 + 31) {            // wave has unmasked work this block
      const bool diag0 = (kb * 64 + 63 > wq0);
      const bool diag1 = (kb * 64 + 63 > wq0 + 16);

      // ---- S^T = K Q^T for both subtiles; each ak read once, used twice
      f32x4 st0[4], st1[4];
      __builtin_amdgcn_s_setprio(1);
      #pragma unroll
      for (int kt = 0; kt < 4; ++kt) {
        st0[kt] = (f32x4){0.f, 0.f, 0.f, 0.f};
        st1[kt] = (f32x4){0.f, 0.f, 0.f, 0.f};
        #pragma unroll
        for (int ks = 0; ks < 4; ++ks) {
          bf16x8 ak = *(const bf16x8*)(Ksb + (kt * 16 + ln) * 128 + ((ks * 32 + lq * 8) ^ xsw));
          st0[kt] = __builtin_amdgcn_mfma_f32_16x16x32_bf16(ak, bq0[ks], st0[kt], 0, 0, 0);
          st1[kt] = __builtin_amdgcn_mfma_f32_16x16x32_bf16(ak, bq1[ks], st1[kt], 0, 0, 0);
        }
      }
      __builtin_amdgcn_s_setprio(0);

      // ---- max-free softmax: p = exp2(s*EXPSC); zero masked; accumulate l
      short4v pf0[4], pf1[4];
      #pragma unroll
      for (int kt = 0; kt < 4; ++kt)
        #pragma unroll
        for (int r = 0; r < 4; ++r) {
          const int key = kb * 64 + kt * 16 + lq * 4 + r;
          float p0 = __builtin_exp2f(st0[kt][r] * EXPSC);
          float p1 = __builtin_exp2f(st1[kt][r] * EXPSC);
          if (diag0 && (key > qg0)) p0 = 0.f;
          if (diag1 && (key > qg1)) p1 = 0.f;
          l0 += p0; l1 += p1;
          pf0[kt][r] = (short)f2b(p0);
          pf1[kt][r] = (short)f2b(p1);
        }

      // ---- O^T += V^T P^T : each av read once, used twice
      __builtin_amdgcn_s_setprio(1);
      #pragma unroll
      for (int kt = 0; kt < 4; ++kt)
        #pragma unroll
        for (int dt = 0; dt < 8; ++dt) {
          short4v av = *(const short4v*)(Vsb + (dt * 16 + ln) * 64 + ((kt * 16 + lq * 4) ^ xsw));
          ot0[dt] = __builtin_amdgcn_mfma_f32_16x16x16bf16_1k(av, pf0[kt], ot0[dt], 0, 0, 0);
          ot1[dt] = __builtin_amdgcn_mfma_f32_16x16x16bf16_1k(av, pf1[kt], ot1[dt], 0, 0, 0);
        }
      __builtin_amdgcn_s_setprio(0);
    }

    __builtin_amdgcn_s_barrier();        // all waves done reading buf[kb&1]
    const int kn = (kb + 2 <= kbmax) ? (kb + 2) : kbmax;  // clamp keeps queue depth
    ATTN_STAGE(kn, smem + (kb & 1) * 16384);
  }

  // ---- final l reduction across the 4 partner lanes (once)
  l0 += __shfl_xor(l0, 16); l0 += __shfl_xor(l0, 32);
  l1 += __shfl_xor(l1, 16); l1 += __shfl_xor(l1, 32);
  const float inv0 = 1.f / l0, inv1 = 1.f / l1;

  // ---- epilogue: O^T -> O via LDS (smem as Os[128][136]), coalesced store.
  asm volatile("s_waitcnt vmcnt(0)" ::: "memory");
  __syncthreads();
  #pragma unroll
  for (int dt = 0; dt < 8; ++dt) {
    ushort4 p4;
    p4.x = f2b(ot0[dt][0] * inv0); p4.y = f2b(ot0[dt][1] * inv0);
    p4.z = f2b(ot0[dt][2] * inv0); p4.w = f2b(ot0[dt][3] * inv0);
    *(ushort4*)(smem + (size_t)(w * 32 + ln) * 136 + dt * 16 + lq * 4) = p4;
    p4.x = f2b(ot1[dt][0] * inv1); p4.y = f2b(ot1[dt][1] * inv1);
    p4.z = f2b(ot1[dt][2] * inv1); p4.w = f2b(ot1[dt][3] * inv1);
    *(ushort4*)(smem + (size_t)(w * 32 + 16 + ln) * 136 + dt * 16 + lq * 4) = p4;
  }
  __syncthreads();
  #pragma unroll
  for (int jj = 0; jj < 8; ++jj) {        // 128 rows x 16 uint4 = 2048 items
    const int s = tid + jj * 256;
    const int row = s >> 4, c8 = s & 15;
    *(uint4*)(qk + (size_t)(b * T_SEQ + qb0 + row) * LQK + h * HD + c8 * 8) =
        *(const uint4*)(smem + row * 136 + c8 * 8);
  }
#undef ATTN_STAGE
}

// ---------------------------------------------------------------- launch
extern "C" void kernel_launch(void* const* d_in, const int* in_sizes, int n_in,
                              void* d_out, int out_size, void* d_ws, size_t ws_size,
                              hipStream_t stream) {
  (void)in_sizes; (void)n_in; (void)out_size;
  const float* x      = (const float*)d_in[0];
  const float* W_attn = (const float*)d_in[1];
  const float* b_attn = (const float*)d_in[2];
  const float* W_proj = (const float*)d_in[3];
  const float* b_proj = (const float*)d_in[4];
  float* out = (float*)d_out;

  char* ws = (char*)d_ws;
  unsigned short* qk = (unsigned short*)(ws);                  // 32 MiB [4096][4096]
  unsigned short* vt = (unsigned short*)(ws + 33554432);       // 16 MiB [B*NH*HD][T]
  unsigned short* xb  = (unsigned short*)(ws + 50331648);      // 16 MiB x bf16
  unsigned short* WaT = (unsigned short*)(ws + 67108864);      // 24 MiB W_attn^T bf16
  unsigned short* WpT = (unsigned short*)(ws + 92274688);      // 8  MiB W_proj^T bf16
  const bool tierA = (ws_size >= 100663296);                   // 96 MiB

  if (tierA) {
    const int NPREP = 8192 + 12288 + 4096;   // cast + W_attn^T + W_proj^T
    prep_all<<<NPREP, 256, 0, stream>>>(x, xb, W_attn, WaT, W_proj, WpT);
    gemm8_bt<1, unsigned short><<<dim3(N_QKV / 256, M_ROWS / 256), 512, 0, stream>>>(
        xb, C_EMB, WaT, C_EMB, b_attn, (unsigned short*)nullptr, 0, qk, vt, C_EMB);
  } else {
    gemm_any<1, float, unsigned short><<<dim3(N_QKV / 128, M_ROWS / 128), 256, 0, stream>>>(
        x, C_EMB, W_attn, N_QKV, b_attn, (unsigned short*)nullptr, 0, qk, vt, N_QKV, C_EMB);
  }

  attn_st<<<dim3(16, NH, B_SZ), 256, 0, stream>>>(qk, vt);

  if (tierA) {
    gemm_bt<0, float><<<dim3(C_EMB / 128, M_ROWS / 128), 256, 0, stream>>>(
        qk, LQK, WpT, b_proj, out, C_EMB, nullptr, nullptr, C_EMB, C_EMB);
  } else {
    gemm_any<0, unsigned short, float><<<dim3(C_EMB / 128, M_ROWS / 128), 256, 0, stream>>>(
        qk, LQK, W_proj, C_EMB, b_proj, out, C_EMB, nullptr, nullptr, C_EMB, C_EMB);
  }
}

// Round 8
// 380.058 us; speedup vs baseline: 1.0345x; 1.0345x over previous
//
#include <hip/hip_runtime.h>
#include <hip/hip_bf16.h>

typedef __bf16 bf16x8 __attribute__((ext_vector_type(8)));
typedef float  f32x4  __attribute__((ext_vector_type(4)));
typedef short  short4v __attribute__((ext_vector_type(4)));

#define B_SZ   2
#define T_SEQ  2048
#define C_EMB  2048
#define NH     16
#define HD     128
#define M_ROWS (B_SZ * T_SEQ)   /* 4096 */
#define N_QKV  (3 * C_EMB)      /* 6144 */
#define LQK    (2 * C_EMB)      /* 4096: qk buffer row length (q|k columns) */

// Global K layout (qk cols [2048,4096)): within-head col c stored at
//   c ^ ((t&7)<<3)   (t = key row). Global V^T layout (vt): within each
// 64-key tile, key col t stored at t ^ ((d&7)<<3) (d = vt row & 127).
// Both swizzles let attn stage tiles LINEARLY via global_load_lds and read
// conflict-free with the same XOR (both-sides involution).

static __device__ __forceinline__ unsigned short f2b(float f) {
  union { __hip_bfloat16 h; unsigned short u; } cv;
  cv.h = __float2bfloat16(f);
  return cv.u;
}
static __device__ __forceinline__ void store_out(float* p, float v) { *p = v; }
static __device__ __forceinline__ void store_out(unsigned short* p, float v) { *p = f2b(v); }

static __device__ __forceinline__ ushort4 load4_bf16(const float* p) {
  float4 v = *(const float4*)p;
  ushort4 o; o.x = f2b(v.x); o.y = f2b(v.y); o.z = f2b(v.z); o.w = f2b(v.w);
  return o;
}
static __device__ __forceinline__ ushort4 load4_bf16(const unsigned short* p) {
  return *(const ushort4*)p;
}

// async global->LDS, 16B/lane; LDS dest must be wave-uniform base + lane*16
static __device__ __forceinline__ void async_cp16(const unsigned short* g, unsigned short* l) {
  __builtin_amdgcn_global_load_lds((__attribute__((address_space(1))) void*)(g),
                                   (__attribute__((address_space(3))) void*)(l), 16, 0, 0);
}

// ---------------------------------------------------------------------------
// Shared epilogue. MODE 0: C = acc + bias. MODE 1 (qkv split): q cols linear;
// k cols swizzled within head; v cols -> vt transposed+swizzled.
// ---------------------------------------------------------------------------
template <int MODE, typename OutT>
static __device__ __forceinline__ void gemm_epilogue(
    f32x4 (&acc)[4][4], const float* __restrict__ bias,
    OutT* __restrict__ C, int ldc,
    unsigned short* __restrict__ qk, unsigned short* __restrict__ vt,
    int bm0, int bn0, int wm, int wn, int ln, int lq) {
  #pragma unroll
  for (int i = 0; i < 4; ++i) {
    const int row0 = bm0 + wm * 64 + i * 16 + lq * 4;
    #pragma unroll
    for (int j = 0; j < 4; ++j) {
      const int col = bn0 + wn * 64 + j * 16 + ln;
      const float bv = bias[col];
      if constexpr (MODE == 0) {
        #pragma unroll
        for (int r = 0; r < 4; ++r)
          store_out(&C[(size_t)(row0 + r) * ldc + col], acc[i][j][r] + bv);
      } else {
        if (bn0 < C_EMB) {              // q columns: linear
          #pragma unroll
          for (int r = 0; r < 4; ++r)
            qk[(size_t)(row0 + r) * LQK + col] = f2b(acc[i][j][r] + bv);
        } else if (bn0 < 2 * C_EMB) {   // k columns: swizzled within head
          #pragma unroll
          for (int r = 0; r < 4; ++r) {
            const int row = row0 + r;
            qk[(size_t)row * LQK + (col & ~127) + ((col & 127) ^ ((row & 7) << 3))] =
                f2b(acc[i][j][r] + bv);
          }
        } else {                        // v columns -> transposed+swizzled store
          const int c2 = col - 2 * C_EMB;           // h*128 + d
          const int bb = row0 >> 11;                // batch
          const int t0 = row0 & (T_SEQ - 1);
          const int vrow = (bb * NH + (c2 >> 7)) * HD + (c2 & 127);
          ushort4 p;
          p.x = f2b(acc[i][j][0] + bv); p.y = f2b(acc[i][j][1] + bv);
          p.z = f2b(acc[i][j][2] + bv); p.w = f2b(acc[i][j][3] + bv);
          *(ushort4*)(vt + (size_t)vrow * T_SEQ + (t0 ^ ((vrow & 7) << 3))) = p;  // stays in 64-tile
        }
      }
    }
  }
}

// ---------------------------------------------------------------------------
// Tier A 128-tile GEMM (m97 structure) — retained for the proj GEMM.
// ---------------------------------------------------------------------------
template <int MODE, typename OutT>
__global__ __launch_bounds__(256) void gemm_bt(const unsigned short* __restrict__ A, int lda,
                                               const unsigned short* __restrict__ Bt,
                                               const float* __restrict__ bias,
                                               OutT* __restrict__ C, int ldc,
                                               unsigned short* __restrict__ qk,
                                               unsigned short* __restrict__ vt,
                                               int N, int K) {
  __shared__ __align__(16) unsigned short As[128 * 32];
  __shared__ __align__(16) unsigned short Bs[128 * 32];
  const int tid = threadIdx.x;
  const int wave = tid >> 6, lane = tid & 63;
  const int wm = wave >> 1, wn = wave & 1;
  const int ln = lane & 15, lq = lane >> 4;
  const int bm0 = blockIdx.y * 128, bn0 = blockIdx.x * 128;

  f32x4 acc[4][4];
  #pragma unroll
  for (int i = 0; i < 4; ++i)
    #pragma unroll
    for (int j = 0; j < 4; ++j) acc[i][j] = (f32x4){0.f, 0.f, 0.f, 0.f};

  const unsigned short* Ag = A  + (size_t)(bm0 + wave * 32 + (lane >> 2)) * lda + (lane & 3) * 8;
  const unsigned short* Bg = Bt + (size_t)(bn0 + wave * 32 + (lane >> 2)) * K   + (lane & 3) * 8;
  unsigned short* Al = As + wave * 1024 + lane * 8;
  unsigned short* Bl = Bs + wave * 1024 + lane * 8;

  for (int k0 = 0; k0 < K; k0 += 32) {
    async_cp16(Ag + k0, Al);
    async_cp16(Ag + k0 + 16 * lda, Al + 512);
    async_cp16(Bg + k0, Bl);
    async_cp16(Bg + k0 + 16 * K, Bl + 512);
    __syncthreads();
    bf16x8 af[4], bfv[4];
    #pragma unroll
    for (int i = 0; i < 4; ++i) {
      af[i]  = *(const bf16x8*)(As + (wm * 64 + i * 16 + ln) * 32 + lq * 8);
      bfv[i] = *(const bf16x8*)(Bs + (wn * 64 + i * 16 + ln) * 32 + lq * 8);
    }
    #pragma unroll
    for (int i = 0; i < 4; ++i)
      #pragma unroll
      for (int j = 0; j < 4; ++j)
        acc[i][j] = __builtin_amdgcn_mfma_f32_16x16x32_bf16(af[i], bfv[j], acc[i][j], 0, 0, 0);
    __syncthreads();
  }
  gemm_epilogue<MODE, OutT>(acc, bias, C, ldc, qk, vt, bm0, bn0, wm, wn, ln, lq);
}

// ---------------------------------------------------------------------------
// 256x256 8-phase GEMM (r5 version — best measured at 125.0 µs).
//   Staging: ph1 A(t1,h0), ph2 A(t1,h1), ph3 B(ta,h0), ph4 B(ta,h1)+VMC4;
//   symmetric ph5-ph8. VMC4 at ph4: queue = [B(t1)4, A(t1)4, B(ta)4] ->
//   drains A(t1) (buf1 complete). At ph8: drains A(ta) (buf0 for next ph1).
//   Tail iteration re-stages current tiles (identical bytes -> benign).
// ---------------------------------------------------------------------------
#define BAR8 __builtin_amdgcn_s_barrier()
#define VMC4 asm volatile("s_waitcnt vmcnt(4)" ::: "memory")

#define STAGE_A8(t, h) do { \
    const unsigned short* g_ = Ag0 + (size_t)((h) * 128) * lda + (t) * 64; \
    unsigned short* l_ = ldsA + ((t) & 1) * 16384 + (h) * 8192 + tid * 8; \
    async_cp16(g_, l_); \
    async_cp16(g_ + (size_t)64 * lda, l_ + 4096); \
  } while (0)
#define STAGE_B8(t, h) do { \
    const unsigned short* g_ = Bg0 + (size_t)((h) * 128) * ldb + (t) * 64; \
    unsigned short* l_ = ldsB + ((t) & 1) * 16384 + (h) * 8192 + tid * 8; \
    async_cp16(g_, l_); \
    async_cp16(g_ + (size_t)64 * ldb, l_ + 4096); \
  } while (0)

#define LOADA8(ab, rq) do { \
    _Pragma("unroll") for (int rt_ = 0; rt_ < 4; ++rt_) { \
      af[rt_][0] = *(const bf16x8*)((ab) + (rq) * 4096 + rt_ * 1024 + kx0); \
      af[rt_][1] = *(const bf16x8*)((ab) + (rq) * 4096 + rt_ * 1024 + kx1); \
    } } while (0)
#define LOADB8(bb, cj0) do { \
    bv_[(cj0)][0]     = *(const bf16x8*)((bb) + (cj0) * 1024 + kx0); \
    bv_[(cj0)][1]     = *(const bf16x8*)((bb) + (cj0) * 1024 + kx1); \
    bv_[(cj0) + 1][0] = *(const bf16x8*)((bb) + ((cj0) + 1) * 1024 + kx0); \
    bv_[(cj0) + 1][1] = *(const bf16x8*)((bb) + ((cj0) + 1) * 1024 + kx1); \
  } while (0)
#define MFMAQ8(rq, cq) do { \
    __builtin_amdgcn_s_setprio(1); \
    _Pragma("unroll") for (int rt_ = 0; rt_ < 4; ++rt_) \
      _Pragma("unroll") for (int ct_ = 0; ct_ < 2; ++ct_) \
        _Pragma("unroll") for (int kk_ = 0; kk_ < 2; ++kk_) \
          acc[(rq) * 4 + rt_][(cq) * 2 + ct_] = __builtin_amdgcn_mfma_f32_16x16x32_bf16( \
              af[rt_][kk_], bv_[(cq) * 2 + ct_][kk_], acc[(rq) * 4 + rt_][(cq) * 2 + ct_], 0, 0, 0); \
    __builtin_amdgcn_s_setprio(0); \
  } while (0)

template <int MODE, typename OutT>
__global__ __launch_bounds__(512, 2) void gemm8_bt(
    const unsigned short* __restrict__ A, int lda,
    const unsigned short* __restrict__ Bt, int ldb,
    const float* __restrict__ bias,
    OutT* __restrict__ C, int ldc,
    unsigned short* __restrict__ qk, unsigned short* __restrict__ vt, int K) {
  __shared__ __align__(16) unsigned short lds8[65536];  // 128 KiB
  unsigned short* ldsA = lds8;
  unsigned short* ldsB = lds8 + 32768;

  const int tid = threadIdx.x;
  const int wave = tid >> 6, lane = tid & 63;
  const int wm = wave >> 2, wn = wave & 3;
  const int ln = lane & 15, lq = lane >> 4;

  const int nbx = gridDim.x;
  int bid = blockIdx.y * nbx + blockIdx.x;
  const int nwg = nbx * gridDim.y;
  if (!(nwg & 7)) bid = (bid & 7) * (nwg >> 3) + (bid >> 3);   // XCD swizzle (bijective: nwg%8==0)
  const int bm0 = (bid / nbx) * 256;
  const int bn0 = (bid % nbx) * 256;

  // staging addressing: thread covers rows (tid>>3) and (tid>>3)+64 of a half,
  // 16B slot (tid&7); pre-swizzled global k-offset = (slot ^ (row&7))*8 shorts.
  const int srow = tid >> 3;
  const int scol = ((tid & 7) ^ (srow & 7)) << 3;
  const unsigned short* Ag0 = A  + (size_t)(bm0 + srow) * lda + scol;
  const unsigned short* Bg0 = Bt + (size_t)(bn0 + srow) * ldb + scol;

  // compute-side swizzled k-offsets (shorts): (ko + lq*8) ^ ((ln&7)<<3)
  const int kx0 = (lq * 8) ^ ((ln & 7) << 3);
  const int kx1 = (32 + lq * 8) ^ ((ln & 7) << 3);
  const unsigned short* Ab0 = lds8 + wm * 8192 + ln * 64;
  const unsigned short* Bb0 = lds8 + 32768 + (wn >> 1) * 8192 + ((wn & 1) * 64 + ln) * 64;
  const unsigned short* Ab1 = Ab0 + 16384;
  const unsigned short* Bb1 = Bb0 + 16384;

  f32x4 acc[8][4];
  #pragma unroll
  for (int i = 0; i < 8; ++i)
    #pragma unroll
    for (int j = 0; j < 4; ++j) acc[i][j] = (f32x4){0.f, 0.f, 0.f, 0.f};
  bf16x8 af[4][2], bv_[4][2];

  // prologue: tile0 fully + tile1's B halves (A(t1) staged at ph1/ph2).
  // 12 issued, VMC4 -> tile0's 8 landed; in flight B(t1)x4 (matches ph1 entry).
  STAGE_A8(0, 0); STAGE_A8(0, 1); STAGE_B8(0, 0); STAGE_B8(0, 1);
  STAGE_B8(1, 0); STAGE_B8(1, 1);
  VMC4;
  BAR8;

  const int NT = K >> 6, NI = NT >> 1;
  for (int i = 0; i < NI; ++i) {
    const int t1 = 2 * i + 1;
    const int ta = (2 * i + 2 < NT) ? (2 * i + 2) : (2 * i);      // tail: restage (same bytes)
    const int tb = (2 * i + 3 < NT) ? (2 * i + 3) : (2 * i + 1);
    // ---- K-tile t0 (buf0)
    LOADA8(Ab0, 0); LOADB8(Bb0, 0); STAGE_A8(t1, 0);        BAR8; MFMAQ8(0, 0); BAR8;  // ph1
    LOADB8(Bb0, 2);                 STAGE_A8(t1, 1);        BAR8; MFMAQ8(0, 1); BAR8;  // ph2
    LOADA8(Ab0, 1);                 STAGE_B8(ta, 0);        BAR8; MFMAQ8(1, 0); BAR8;  // ph3
                                    STAGE_B8(ta, 1); VMC4;  BAR8; MFMAQ8(1, 1); BAR8;  // ph4
    // ---- K-tile t1 (buf1)
    LOADA8(Ab1, 0); LOADB8(Bb1, 0); STAGE_A8(ta, 0);        BAR8; MFMAQ8(0, 0); BAR8;  // ph5
    LOADB8(Bb1, 2);                 STAGE_A8(ta, 1);        BAR8; MFMAQ8(0, 1); BAR8;  // ph6
    LOADA8(Ab1, 1);                 STAGE_B8(tb, 0);        BAR8; MFMAQ8(1, 0); BAR8;  // ph7
                                    STAGE_B8(tb, 1); VMC4;  BAR8; MFMAQ8(1, 1); BAR8;  // ph8
  }

  // ---- epilogue: wave rows bm0+wm*128+ri*16+lq*4+r, cols bn0+wn*64+cj*16+ln
  #pragma unroll
  for (int ri = 0; ri < 8; ++ri) {
    const int row0 = bm0 + wm * 128 + ri * 16 + lq * 4;
    #pragma unroll
    for (int cj = 0; cj < 4; ++cj) {
      const int col = bn0 + wn * 64 + cj * 16 + ln;
      const float bvs = bias[col];
      if constexpr (MODE == 0) {
        #pragma unroll
        for (int r = 0; r < 4; ++r)
          store_out(&C[(size_t)(row0 + r) * ldc + col], acc[ri][cj][r] + bvs);
      } else {
        if (bn0 < C_EMB) {              // q cols: linear (256-tile never straddles)
          #pragma unroll
          for (int r = 0; r < 4; ++r)
            qk[(size_t)(row0 + r) * LQK + col] = f2b(acc[ri][cj][r] + bvs);
        } else if (bn0 < 2 * C_EMB) {   // k cols: swizzled within head
          #pragma unroll
          for (int r = 0; r < 4; ++r) {
            const int row = row0 + r;
            qk[(size_t)row * LQK + (col & ~127) + ((col & 127) ^ ((row & 7) << 3))] =
                f2b(acc[ri][cj][r] + bvs);
          }
        } else {                        // v cols -> transposed+swizzled store into vt
          const int c2 = col - 2 * C_EMB;
          const int bb = row0 >> 11;
          const int t0v = row0 & (T_SEQ - 1);
          const int vrow = (bb * NH + (c2 >> 7)) * HD + (c2 & 127);
          ushort4 p;
          p.x = f2b(acc[ri][cj][0] + bvs); p.y = f2b(acc[ri][cj][1] + bvs);
          p.z = f2b(acc[ri][cj][2] + bvs); p.w = f2b(acc[ri][cj][3] + bvs);
          *(ushort4*)(vt + (size_t)vrow * T_SEQ + (t0v ^ ((vrow & 7) << 3))) = p;
        }
      }
    }
  }
}

// ---------------------------------------------------------------------------
// Tier B GEMM fallback (validated round-2 structure).
// ---------------------------------------------------------------------------
template <int MODE, typename AT, typename OutT>
__global__ __launch_bounds__(256) void gemm_any(const AT* __restrict__ A, int lda,
                                                const float* __restrict__ B, int ldb,
                                                const float* __restrict__ bias,
                                                OutT* __restrict__ C, int ldc,
                                                unsigned short* __restrict__ qk,
                                                unsigned short* __restrict__ vt,
                                                int N, int K) {
  __shared__ __align__(16) unsigned short As[128 * 32];
  __shared__ __align__(16) unsigned short Bs[128 * 32];
  __shared__ __align__(16) float Bstage[32 * 132];

  const int tid = threadIdx.x;
  const int wave = tid >> 6, lane = tid & 63;
  const int wm = wave >> 1, wn = wave & 1;
  const int ln = lane & 15, lq = lane >> 4;
  const int bm0 = blockIdx.y * 128, bn0 = blockIdx.x * 128;

  f32x4 acc[4][4];
  #pragma unroll
  for (int i = 0; i < 4; ++i)
    #pragma unroll
    for (int j = 0; j < 4; ++j) acc[i][j] = (f32x4){0.f, 0.f, 0.f, 0.f};

  for (int k0 = 0; k0 < K; k0 += 32) {
    #pragma unroll
    for (int j = 0; j < 4; ++j) {
      const int item = tid + j * 256;
      const int m = item >> 3;
      const int kf = (item & 7) * 4;
      *(ushort4*)(As + m * 32 + kf) = load4_bf16(A + (size_t)(bm0 + m) * lda + k0 + kf);
    }
    #pragma unroll
    for (int j = 0; j < 4; ++j) {
      const int item = tid + j * 256;
      const int kr = item >> 5;
      const int nf = (item & 31) * 4;
      *(float4*)(Bstage + kr * 132 + nf) =
          *(const float4*)(B + (size_t)(k0 + kr) * ldb + bn0 + nf);
    }
    __syncthreads();
    #pragma unroll
    for (int j = 0; j < 4; ++j) {
      const int item = tid + j * 256;
      const int n = item >> 3;
      const int kq = item & 7;
      const int k = kq * 4;
      ushort4 h4;
      h4.x = f2b(Bstage[(k + 0) * 132 + n]);
      h4.y = f2b(Bstage[(k + 1) * 132 + n]);
      h4.z = f2b(Bstage[(k + 2) * 132 + n]);
      h4.w = f2b(Bstage[(k + 3) * 132 + n]);
      *(ushort4*)(Bs + n * 32 + (((kq >> 1) ^ (n & 3)) << 3) + ((kq & 1) << 2)) = h4;
    }
    __syncthreads();
    bf16x8 af[4], bfv[4];
    #pragma unroll
    for (int i = 0; i < 4; ++i) {
      af[i] = *(const bf16x8*)(As + (wm * 64 + i * 16 + ln) * 32 + lq * 8);
      const int n = wn * 64 + i * 16 + ln;
      bfv[i] = *(const bf16x8*)(Bs + n * 32 + ((lq ^ (n & 3)) << 3));
    }
    #pragma unroll
    for (int i = 0; i < 4; ++i)
      #pragma unroll
      for (int j = 0; j < 4; ++j)
        acc[i][j] = __builtin_amdgcn_mfma_f32_16x16x32_bf16(af[i], bfv[j], acc[i][j], 0, 0, 0);
    __syncthreads();
  }
  gemm_epilogue<MODE, OutT>(acc, bias, C, ldc, qk, vt, bm0, bn0, wm, wn, ln, lq);
}

// --------------------------------------------------------------- prep (fused)
static __device__ __forceinline__ void transpose_body(
    const float* __restrict__ in, unsigned short* __restrict__ out,
    int R, int Cc, int bx, int by, float (*t)[33]) {
  const int tx = threadIdx.x & 31, ty = threadIdx.x >> 5;
  #pragma unroll
  for (int j = 0; j < 32; j += 8)
    t[ty + j][tx] = in[(size_t)(by + ty + j) * Cc + bx + tx];
  __syncthreads();
  #pragma unroll
  for (int j = 0; j < 32; j += 8)
    out[(size_t)(bx + ty + j) * R + by + tx] = f2b(t[tx][ty + j]);
}

__global__ __launch_bounds__(256) void prep_all(
    const float* __restrict__ x, unsigned short* __restrict__ xb,
    const float* __restrict__ Wa, unsigned short* __restrict__ WaT,
    const float* __restrict__ Wp, unsigned short* __restrict__ WpT) {
  __shared__ float t[32][33];
  const int NCAST = (M_ROWS * C_EMB / 4) / 256;        // 8192
  const int NTA_X = N_QKV / 32;                        // 192
  const int NTA   = NTA_X * (C_EMB / 32);              // 12288
  const int NTP_X = C_EMB / 32;                        // 64
  const int bid = blockIdx.x;
  if (bid < NCAST) {
    const int i = bid * 256 + threadIdx.x;
    float4 v = ((const float4*)x)[i];
    ushort4 o; o.x = f2b(v.x); o.y = f2b(v.y); o.z = f2b(v.z); o.w = f2b(v.w);
    ((ushort4*)xb)[i] = o;
  } else if (bid < NCAST + NTA) {
    const int tb = bid - NCAST;
    transpose_body(Wa, WaT, C_EMB, N_QKV, (tb % NTA_X) * 32, (tb / NTA_X) * 32, t);
  } else {
    const int tb = bid - NCAST - NTA;
    transpose_body(Wp, WpT, C_EMB, C_EMB, (tb % NTP_X) * 32, (tb / NTP_X) * 32, t);
  }
}

// ---------------------------------------------------------------------------
// Flash attention (r5/r6 512-thread version — best measured; r7's 4-wave
// 32q/wave variant regressed ~23 µs by halving occupancy 16->8 waves/CU).
// 8 waves x 16 q; double-buffered K/V via global_load_lds (swizzle baked
// into global layout); counted vmcnt(4) + raw s_barrier; setprio on MFMA.
// ---------------------------------------------------------------------------
__global__ __launch_bounds__(512, 4) void attn_st(unsigned short* __restrict__ qk,
                                                  const unsigned short* __restrict__ vt) {
  // 2 buffers x (K [64][128] + V^T [128][64]) = 2 x 16384 shorts = 64 KiB.
  // Epilogue reuses [0..17408) as Os[128][136].
  __shared__ __align__(16) unsigned short smem[32768];

  const int tid = threadIdx.x;
  const int w = tid >> 6, lane = tid & 63;
  const int ln = lane & 15, lq = lane >> 4;
  const int b = blockIdx.z, h = blockIdx.y;
  const int j = (b == 0) ? (15 - (int)blockIdx.x) : (int)blockIdx.x;
  const int qb0 = j * 128;
  const float EXPSC = 0.08838834764831845f * 1.4426950408889634f;
  const int xsw = (ln & 7) << 3;   // read-side XOR (row&7 == ln&7 for both K and V reads)

  // Q fragments (B-operand: n=ln=query, k=lq*8..) straight from global, once
  const int wq0 = qb0 + w * 16;
  const int qg = wq0 + ln;
  const unsigned short* Qp = qk + (size_t)(b * T_SEQ + qg) * LQK + h * HD + lq * 8;
  bf16x8 bq[4];
  #pragma unroll
  for (int ks = 0; ks < 4; ++ks) bq[ks] = *(const bf16x8*)(Qp + ks * 32);

  // staging bases (global layouts pre-swizzled -> linear row copies)
  const unsigned short* Kg = qk + (size_t)(b * T_SEQ) * LQK + C_EMB + h * HD;
  const unsigned short* Vg = vt + ((size_t)(b * NH + h) * HD) * T_SEQ;
  const int krow = tid >> 4, kc16 = (tid & 15) * 8;   // K: 32 rows/chunk x 16 slots
  const int vrow = tid >> 3, vc16 = (tid & 7) * 8;    // V: 64 rows/chunk x 8 slots

  f32x4 ot[8];  // O^T accum: regs = d = dt*16+lq*4+r, col = query ln
  #pragma unroll
  for (int dt = 0; dt < 8; ++dt) ot[dt] = (f32x4){0.f, 0.f, 0.f, 0.f};
  float l_i = 0.f;

  // prologue: stage tiles 0 (buf0) and 1 (buf1): 4 cp16/thread each
  {
    unsigned short* b0 = smem;
    async_cp16(Kg + (size_t)(0 * 64 + krow) * LQK + kc16,        b0 + tid * 8);
    async_cp16(Kg + (size_t)(0 * 64 + krow + 32) * LQK + kc16,   b0 + 4096 + tid * 8);
    async_cp16(Vg + (size_t)vrow * T_SEQ + 0 * 64 + vc16,        b0 + 8192 + tid * 8);
    async_cp16(Vg + (size_t)(vrow + 64) * T_SEQ + 0 * 64 + vc16, b0 + 12288 + tid * 8);
    unsigned short* b1 = smem + 16384;
    async_cp16(Kg + (size_t)(1 * 64 + krow) * LQK + kc16,        b1 + tid * 8);
    async_cp16(Kg + (size_t)(1 * 64 + krow + 32) * LQK + kc16,   b1 + 4096 + tid * 8);
    async_cp16(Vg + (size_t)vrow * T_SEQ + 1 * 64 + vc16,        b1 + 8192 + tid * 8);
    async_cp16(Vg + (size_t)(vrow + 64) * T_SEQ + 1 * 64 + vc16, b1 + 12288 + tid * 8);
  }

  const int kbmax = 2 * j + 1;
  for (int kb = 0; kb <= kbmax; ++kb) {
    asm volatile("s_waitcnt vmcnt(4)" ::: "memory");  // tile kb landed (tile kb+1 in flight)
    __builtin_amdgcn_s_barrier();
    const unsigned short* Ksb = smem + (kb & 1) * 16384;
    const unsigned short* Vsb = Ksb + 8192;

    if (kb * 64 <= wq0 + 15) {            // wave has unmasked work this block
      const bool diag = (kb * 64 + 63 > wq0);

      // ---- S^T = K Q^T
      f32x4 st[4];
      __builtin_amdgcn_s_setprio(1);
      #pragma unroll
      for (int kt = 0; kt < 4; ++kt) {
        st[kt] = (f32x4){0.f, 0.f, 0.f, 0.f};
        #pragma unroll
        for (int ks = 0; ks < 4; ++ks) {
          bf16x8 ak = *(const bf16x8*)(Ksb + (kt * 16 + ln) * 128 + ((ks * 32 + lq * 8) ^ xsw));
          st[kt] = __builtin_amdgcn_mfma_f32_16x16x32_bf16(ak, bq[ks], st[kt], 0, 0, 0);
        }
      }
      __builtin_amdgcn_s_setprio(0);

      // ---- max-free softmax: p = exp2(s*EXPSC); zero masked; accumulate l
      short4v pf[4];
      #pragma unroll
      for (int kt = 0; kt < 4; ++kt)
        #pragma unroll
        for (int r = 0; r < 4; ++r) {
          float p = __builtin_exp2f(st[kt][r] * EXPSC);
          if (diag && (kb * 64 + kt * 16 + lq * 4 + r > qg)) p = 0.f;
          l_i += p;
          pf[kt][r] = (short)f2b(p);
        }

      // ---- O^T += V^T P^T : K=16 MFMA, P straight from registers
      __builtin_amdgcn_s_setprio(1);
      #pragma unroll
      for (int kt = 0; kt < 4; ++kt)
        #pragma unroll
        for (int dt = 0; dt < 8; ++dt) {
          short4v av = *(const short4v*)(Vsb + (dt * 16 + ln) * 64 + ((kt * 16 + lq * 4) ^ xsw));
          ot[dt] = __builtin_amdgcn_mfma_f32_16x16x16bf16_1k(av, pf[kt], ot[dt], 0, 0, 0);
        }
      __builtin_amdgcn_s_setprio(0);
    }

    __builtin_amdgcn_s_barrier();        // all waves done reading buf[kb&1]
    const int kn = (kb + 2 <= kbmax) ? (kb + 2) : kbmax;  // clamp keeps queue depth
    unsigned short* dst = smem + (kb & 1) * 16384;
    async_cp16(Kg + (size_t)(kn * 64 + krow) * LQK + kc16,        dst + tid * 8);
    async_cp16(Kg + (size_t)(kn * 64 + krow + 32) * LQK + kc16,   dst + 4096 + tid * 8);
    async_cp16(Vg + (size_t)vrow * T_SEQ + kn * 64 + vc16,        dst + 8192 + tid * 8);
    async_cp16(Vg + (size_t)(vrow + 64) * T_SEQ + kn * 64 + vc16, dst + 12288 + tid * 8);
  }

  // ---- final l reduction across the 4 partner lanes (once)
  l_i += __shfl_xor(l_i, 16);
  l_i += __shfl_xor(l_i, 32);
  const float inv = 1.f / l_i;

  // ---- epilogue: O^T -> O via LDS (smem as Os[128][136]), coalesced store.
  // Drain in-flight staging before reusing smem.
  asm volatile("s_waitcnt vmcnt(0)" ::: "memory");
  __syncthreads();
  #pragma unroll
  for (int dt = 0; dt < 8; ++dt) {
    ushort4 p4;
    p4.x = f2b(ot[dt][0] * inv); p4.y = f2b(ot[dt][1] * inv);
    p4.z = f2b(ot[dt][2] * inv); p4.w = f2b(ot[dt][3] * inv);
    *(ushort4*)(smem + (w * 16 + ln) * 136 + dt * 16 + lq * 4) = p4;
  }
  __syncthreads();
  #pragma unroll
  for (int jj = 0; jj < 4; ++jj) {        // 128 rows x 16 uint4 = 2048 items
    const int s = tid + jj * 512;
    const int row = s >> 4, c8 = s & 15;
    *(uint4*)(qk + (size_t)(b * T_SEQ + qb0 + row) * LQK + h * HD + c8 * 8) =
        *(const uint4*)(smem + row * 136 + c8 * 8);
  }
}

// ---------------------------------------------------------------- launch
extern "C" void kernel_launch(void* const* d_in, const int* in_sizes, int n_in,
                              void* d_out, int out_size, void* d_ws, size_t ws_size,
                              hipStream_t stream) {
  (void)in_sizes; (void)n_in; (void)out_size;
  const float* x      = (const float*)d_in[0];
  const float* W_attn = (const float*)d_in[1];
  const float* b_attn = (const float*)d_in[2];
  const float* W_proj = (const float*)d_in[3];
  const float* b_proj = (const float*)d_in[4];
  float* out = (float*)d_out;

  char* ws = (char*)d_ws;
  unsigned short* qk = (unsigned short*)(ws);                  // 32 MiB [4096][4096]
  unsigned short* vt = (unsigned short*)(ws + 33554432);       // 16 MiB [B*NH*HD][T]
  unsigned short* xb  = (unsigned short*)(ws + 50331648);      // 16 MiB x bf16
  unsigned short* WaT = (unsigned short*)(ws + 67108864);      // 24 MiB W_attn^T bf16
  unsigned short* WpT = (unsigned short*)(ws + 92274688);      // 8  MiB W_proj^T bf16
  const bool tierA = (ws_size >= 100663296);                   // 96 MiB

  if (tierA) {
    const int NPREP = 8192 + 12288 + 4096;   // cast + W_attn^T + W_proj^T
    prep_all<<<NPREP, 256, 0, stream>>>(x, xb, W_attn, WaT, W_proj, WpT);
    gemm8_bt<1, unsigned short><<<dim3(N_QKV / 256, M_ROWS / 256), 512, 0, stream>>>(
        xb, C_EMB, WaT, C_EMB, b_attn, (unsigned short*)nullptr, 0, qk, vt, C_EMB);
  } else {
    gemm_any<1, float, unsigned short><<<dim3(N_QKV / 128, M_ROWS / 128), 256, 0, stream>>>(
        x, C_EMB, W_attn, N_QKV, b_attn, (unsigned short*)nullptr, 0, qk, vt, N_QKV, C_EMB);
  }

  attn_st<<<dim3(16, NH, B_SZ), 512, 0, stream>>>(qk, vt);

  if (tierA) {
    gemm_bt<0, float><<<dim3(C_EMB / 128, M_ROWS / 128), 256, 0, stream>>>(
        qk, LQK, WpT, b_proj, out, C_EMB, nullptr, nullptr, C_EMB, C_EMB);
  } else {
    gemm_any<0, unsigned short, float><<<dim3(C_EMB / 128, M_ROWS / 128), 256, 0, stream>>>(
        qk, LQK, W_proj, C_EMB, b_proj, out, C_EMB, nullptr, nullptr, C_EMB, C_EMB);
  }
}

// Round 9
// 362.644 us; speedup vs baseline: 1.0842x; 1.0480x over previous
//
#include <hip/hip_runtime.h>
#include <hip/hip_bf16.h>

typedef __bf16 bf16x8 __attribute__((ext_vector_type(8)));
typedef float  f32x4  __attribute__((ext_vector_type(4)));
typedef short  short4v __attribute__((ext_vector_type(4)));

#define B_SZ   2
#define T_SEQ  2048
#define C_EMB  2048
#define NH     16
#define HD     128
#define M_ROWS (B_SZ * T_SEQ)   /* 4096 */
#define N_QKV  (3 * C_EMB)      /* 6144 */
#define LQK    (2 * C_EMB)      /* 4096: qk buffer row length (q|k columns) */

// Global K layout (qk cols [2048,4096)): within-head col c stored at
//   c ^ ((t&7)<<3)   (t = key row). Global V^T layout (vt): within each
// 64-key tile, key col t stored at t ^ ((d&7)<<3) (d = vt row & 127).
// Both swizzles let attn stage tiles LINEARLY via global_load_lds and read
// conflict-free with the same XOR (both-sides involution).

static __device__ __forceinline__ unsigned short f2b(float f) {
  union { __hip_bfloat16 h; unsigned short u; } cv;
  cv.h = __float2bfloat16(f);
  return cv.u;
}
static __device__ __forceinline__ void store_out(float* p, float v) { *p = v; }
static __device__ __forceinline__ void store_out(unsigned short* p, float v) { *p = f2b(v); }

static __device__ __forceinline__ ushort4 load4_bf16(const float* p) {
  float4 v = *(const float4*)p;
  ushort4 o; o.x = f2b(v.x); o.y = f2b(v.y); o.z = f2b(v.z); o.w = f2b(v.w);
  return o;
}
static __device__ __forceinline__ ushort4 load4_bf16(const unsigned short* p) {
  return *(const ushort4*)p;
}

// async global->LDS, 16B/lane; LDS dest must be wave-uniform base + lane*16
static __device__ __forceinline__ void async_cp16(const unsigned short* g, unsigned short* l) {
  __builtin_amdgcn_global_load_lds((__attribute__((address_space(1))) void*)(g),
                                   (__attribute__((address_space(3))) void*)(l), 16, 0, 0);
}

// ---------------------------------------------------------------------------
// Shared epilogue. MODE 0: C = acc + bias. MODE 1 (qkv split): q cols linear;
// k cols swizzled within head; v cols -> vt transposed+swizzled.
// Works for any wave grid with wm-stride 64 rows / wn-stride 64 cols.
// ---------------------------------------------------------------------------
template <int MODE, typename OutT>
static __device__ __forceinline__ void gemm_epilogue(
    f32x4 (&acc)[4][4], const float* __restrict__ bias,
    OutT* __restrict__ C, int ldc,
    unsigned short* __restrict__ qk, unsigned short* __restrict__ vt,
    int bm0, int bn0, int wm, int wn, int ln, int lq) {
  #pragma unroll
  for (int i = 0; i < 4; ++i) {
    const int row0 = bm0 + wm * 64 + i * 16 + lq * 4;
    #pragma unroll
    for (int j = 0; j < 4; ++j) {
      const int col = bn0 + wn * 64 + j * 16 + ln;
      const float bv = bias[col];
      if constexpr (MODE == 0) {
        #pragma unroll
        for (int r = 0; r < 4; ++r)
          store_out(&C[(size_t)(row0 + r) * ldc + col], acc[i][j][r] + bv);
      } else {
        if (bn0 < C_EMB) {              // q columns: linear
          #pragma unroll
          for (int r = 0; r < 4; ++r)
            qk[(size_t)(row0 + r) * LQK + col] = f2b(acc[i][j][r] + bv);
        } else if (bn0 < 2 * C_EMB) {   // k columns: swizzled within head
          #pragma unroll
          for (int r = 0; r < 4; ++r) {
            const int row = row0 + r;
            qk[(size_t)row * LQK + (col & ~127) + ((col & 127) ^ ((row & 7) << 3))] =
                f2b(acc[i][j][r] + bv);
          }
        } else {                        // v columns -> transposed+swizzled store
          const int c2 = col - 2 * C_EMB;           // h*128 + d
          const int bb = row0 >> 11;                // batch
          const int t0 = row0 & (T_SEQ - 1);
          const int vrow = (bb * NH + (c2 >> 7)) * HD + (c2 & 127);
          ushort4 p;
          p.x = f2b(acc[i][j][0] + bv); p.y = f2b(acc[i][j][1] + bv);
          p.z = f2b(acc[i][j][2] + bv); p.w = f2b(acc[i][j][3] + bv);
          *(ushort4*)(vt + (size_t)vrow * T_SEQ + (t0 ^ ((vrow & 7) << 3))) = p;  // stays in 64-tile
        }
      }
    }
  }
}

// ---------------------------------------------------------------------------
// Tier A 128-tile GEMM (m97 structure) — kept for Tier B symmetry.
// ---------------------------------------------------------------------------
template <int MODE, typename OutT>
__global__ __launch_bounds__(256) void gemm_bt(const unsigned short* __restrict__ A, int lda,
                                               const unsigned short* __restrict__ Bt,
                                               const float* __restrict__ bias,
                                               OutT* __restrict__ C, int ldc,
                                               unsigned short* __restrict__ qk,
                                               unsigned short* __restrict__ vt,
                                               int N, int K) {
  __shared__ __align__(16) unsigned short As[128 * 32];
  __shared__ __align__(16) unsigned short Bs[128 * 32];
  const int tid = threadIdx.x;
  const int wave = tid >> 6, lane = tid & 63;
  const int wm = wave >> 1, wn = wave & 1;
  const int ln = lane & 15, lq = lane >> 4;
  const int bm0 = blockIdx.y * 128, bn0 = blockIdx.x * 128;

  f32x4 acc[4][4];
  #pragma unroll
  for (int i = 0; i < 4; ++i)
    #pragma unroll
    for (int j = 0; j < 4; ++j) acc[i][j] = (f32x4){0.f, 0.f, 0.f, 0.f};

  const unsigned short* Ag = A  + (size_t)(bm0 + wave * 32 + (lane >> 2)) * lda + (lane & 3) * 8;
  const unsigned short* Bg = Bt + (size_t)(bn0 + wave * 32 + (lane >> 2)) * K   + (lane & 3) * 8;
  unsigned short* Al = As + wave * 1024 + lane * 8;
  unsigned short* Bl = Bs + wave * 1024 + lane * 8;

  for (int k0 = 0; k0 < K; k0 += 32) {
    async_cp16(Ag + k0, Al);
    async_cp16(Ag + k0 + 16 * lda, Al + 512);
    async_cp16(Bg + k0, Bl);
    async_cp16(Bg + k0 + 16 * K, Bl + 512);
    __syncthreads();
    bf16x8 af[4], bfv[4];
    #pragma unroll
    for (int i = 0; i < 4; ++i) {
      af[i]  = *(const bf16x8*)(As + (wm * 64 + i * 16 + ln) * 32 + lq * 8);
      bfv[i] = *(const bf16x8*)(Bs + (wn * 64 + i * 16 + ln) * 32 + lq * 8);
    }
    #pragma unroll
    for (int i = 0; i < 4; ++i)
      #pragma unroll
      for (int j = 0; j < 4; ++j)
        acc[i][j] = __builtin_amdgcn_mfma_f32_16x16x32_bf16(af[i], bfv[j], acc[i][j], 0, 0, 0);
    __syncthreads();
  }
  gemm_epilogue<MODE, OutT>(acc, bias, C, ldc, qk, vt, bm0, bn0, wm, wn, ln, lq);
}

// ---------------------------------------------------------------------------
// 256x256 8-phase GEMM (r5 version — best measured; used for qkv).
//   Staging: ph1 A(t1,h0), ph2 A(t1,h1), ph3 B(ta,h0), ph4 B(ta,h1)+VMC4;
//   symmetric ph5-ph8. VMC4 at ph4: queue = [B(t1)4, A(t1)4, B(ta)4] ->
//   drains A(t1) (buf1 complete). At ph8: drains A(ta) (buf0 for next ph1).
//   Tail iteration re-stages current tiles (identical bytes -> benign).
// ---------------------------------------------------------------------------
#define BAR8 __builtin_amdgcn_s_barrier()
#define VMC4 asm volatile("s_waitcnt vmcnt(4)" ::: "memory")
#define VMC2 asm volatile("s_waitcnt vmcnt(2)" ::: "memory")

#define STAGE_A8(t, h) do { \
    const unsigned short* g_ = Ag0 + (size_t)((h) * 128) * lda + (t) * 64; \
    unsigned short* l_ = ldsA + ((t) & 1) * 16384 + (h) * 8192 + tid * 8; \
    async_cp16(g_, l_); \
    async_cp16(g_ + (size_t)64 * lda, l_ + 4096); \
  } while (0)
#define STAGE_B8(t, h) do { \
    const unsigned short* g_ = Bg0 + (size_t)((h) * 128) * ldb + (t) * 64; \
    unsigned short* l_ = ldsB + ((t) & 1) * 16384 + (h) * 8192 + tid * 8; \
    async_cp16(g_, l_); \
    async_cp16(g_ + (size_t)64 * ldb, l_ + 4096); \
  } while (0)

#define LOADA8(ab, rq) do { \
    _Pragma("unroll") for (int rt_ = 0; rt_ < 4; ++rt_) { \
      af[rt_][0] = *(const bf16x8*)((ab) + (rq) * 4096 + rt_ * 1024 + kx0); \
      af[rt_][1] = *(const bf16x8*)((ab) + (rq) * 4096 + rt_ * 1024 + kx1); \
    } } while (0)
#define LOADB8(bb, cj0) do { \
    bv_[(cj0)][0]     = *(const bf16x8*)((bb) + (cj0) * 1024 + kx0); \
    bv_[(cj0)][1]     = *(const bf16x8*)((bb) + (cj0) * 1024 + kx1); \
    bv_[(cj0) + 1][0] = *(const bf16x8*)((bb) + ((cj0) + 1) * 1024 + kx0); \
    bv_[(cj0) + 1][1] = *(const bf16x8*)((bb) + ((cj0) + 1) * 1024 + kx1); \
  } while (0)
#define MFMAQ8(rq, cq) do { \
    __builtin_amdgcn_s_setprio(1); \
    _Pragma("unroll") for (int rt_ = 0; rt_ < 4; ++rt_) \
      _Pragma("unroll") for (int ct_ = 0; ct_ < 2; ++ct_) \
        _Pragma("unroll") for (int kk_ = 0; kk_ < 2; ++kk_) \
          acc[(rq) * 4 + rt_][(cq) * 2 + ct_] = __builtin_amdgcn_mfma_f32_16x16x32_bf16( \
              af[rt_][kk_], bv_[(cq) * 2 + ct_][kk_], acc[(rq) * 4 + rt_][(cq) * 2 + ct_], 0, 0, 0); \
    __builtin_amdgcn_s_setprio(0); \
  } while (0)

template <int MODE, typename OutT>
__global__ __launch_bounds__(512, 2) void gemm8_bt(
    const unsigned short* __restrict__ A, int lda,
    const unsigned short* __restrict__ Bt, int ldb,
    const float* __restrict__ bias,
    OutT* __restrict__ C, int ldc,
    unsigned short* __restrict__ qk, unsigned short* __restrict__ vt, int K) {
  __shared__ __align__(16) unsigned short lds8[65536];  // 128 KiB
  unsigned short* ldsA = lds8;
  unsigned short* ldsB = lds8 + 32768;

  const int tid = threadIdx.x;
  const int wave = tid >> 6, lane = tid & 63;
  const int wm = wave >> 2, wn = wave & 3;
  const int ln = lane & 15, lq = lane >> 4;

  const int nbx = gridDim.x;
  int bid = blockIdx.y * nbx + blockIdx.x;
  const int nwg = nbx * gridDim.y;
  if (!(nwg & 7)) bid = (bid & 7) * (nwg >> 3) + (bid >> 3);   // XCD swizzle (bijective: nwg%8==0)
  const int bm0 = (bid / nbx) * 256;
  const int bn0 = (bid % nbx) * 256;

  // staging addressing: thread covers rows (tid>>3) and (tid>>3)+64 of a half,
  // 16B slot (tid&7); pre-swizzled global k-offset = (slot ^ (row&7))*8 shorts.
  const int srow = tid >> 3;
  const int scol = ((tid & 7) ^ (srow & 7)) << 3;
  const unsigned short* Ag0 = A  + (size_t)(bm0 + srow) * lda + scol;
  const unsigned short* Bg0 = Bt + (size_t)(bn0 + srow) * ldb + scol;

  // compute-side swizzled k-offsets (shorts): (ko + lq*8) ^ ((ln&7)<<3)
  const int kx0 = (lq * 8) ^ ((ln & 7) << 3);
  const int kx1 = (32 + lq * 8) ^ ((ln & 7) << 3);
  const unsigned short* Ab0 = lds8 + wm * 8192 + ln * 64;
  const unsigned short* Bb0 = lds8 + 32768 + (wn >> 1) * 8192 + ((wn & 1) * 64 + ln) * 64;
  const unsigned short* Ab1 = Ab0 + 16384;
  const unsigned short* Bb1 = Bb0 + 16384;

  f32x4 acc[8][4];
  #pragma unroll
  for (int i = 0; i < 8; ++i)
    #pragma unroll
    for (int j = 0; j < 4; ++j) acc[i][j] = (f32x4){0.f, 0.f, 0.f, 0.f};
  bf16x8 af[4][2], bv_[4][2];

  // prologue: tile0 fully + tile1's B halves (A(t1) staged at ph1/ph2).
  // 12 issued, VMC4 -> tile0's 8 landed; in flight B(t1)x4 (matches ph1 entry).
  STAGE_A8(0, 0); STAGE_A8(0, 1); STAGE_B8(0, 0); STAGE_B8(0, 1);
  STAGE_B8(1, 0); STAGE_B8(1, 1);
  VMC4;
  BAR8;

  const int NT = K >> 6, NI = NT >> 1;
  for (int i = 0; i < NI; ++i) {
    const int t1 = 2 * i + 1;
    const int ta = (2 * i + 2 < NT) ? (2 * i + 2) : (2 * i);      // tail: restage (same bytes)
    const int tb = (2 * i + 3 < NT) ? (2 * i + 3) : (2 * i + 1);
    // ---- K-tile t0 (buf0)
    LOADA8(Ab0, 0); LOADB8(Bb0, 0); STAGE_A8(t1, 0);        BAR8; MFMAQ8(0, 0); BAR8;  // ph1
    LOADB8(Bb0, 2);                 STAGE_A8(t1, 1);        BAR8; MFMAQ8(0, 1); BAR8;  // ph2
    LOADA8(Ab0, 1);                 STAGE_B8(ta, 0);        BAR8; MFMAQ8(1, 0); BAR8;  // ph3
                                    STAGE_B8(ta, 1); VMC4;  BAR8; MFMAQ8(1, 1); BAR8;  // ph4
    // ---- K-tile t1 (buf1)
    LOADA8(Ab1, 0); LOADB8(Bb1, 0); STAGE_A8(ta, 0);        BAR8; MFMAQ8(0, 0); BAR8;  // ph5
    LOADB8(Bb1, 2);                 STAGE_A8(ta, 1);        BAR8; MFMAQ8(0, 1); BAR8;  // ph6
    LOADA8(Ab1, 1);                 STAGE_B8(tb, 0);        BAR8; MFMAQ8(1, 0); BAR8;  // ph7
                                    STAGE_B8(tb, 1); VMC4;  BAR8; MFMAQ8(1, 1); BAR8;  // ph8
  }

  // ---- epilogue: wave rows bm0+wm*128+ri*16+lq*4+r, cols bn0+wn*64+cj*16+ln
  #pragma unroll
  for (int ri = 0; ri < 8; ++ri) {
    const int row0 = bm0 + wm * 128 + ri * 16 + lq * 4;
    #pragma unroll
    for (int cj = 0; cj < 4; ++cj) {
      const int col = bn0 + wn * 64 + cj * 16 + ln;
      const float bvs = bias[col];
      if constexpr (MODE == 0) {
        #pragma unroll
        for (int r = 0; r < 4; ++r)
          store_out(&C[(size_t)(row0 + r) * ldc + col], acc[ri][cj][r] + bvs);
      } else {
        if (bn0 < C_EMB) {              // q cols: linear (256-tile never straddles)
          #pragma unroll
          for (int r = 0; r < 4; ++r)
            qk[(size_t)(row0 + r) * LQK + col] = f2b(acc[ri][cj][r] + bvs);
        } else if (bn0 < 2 * C_EMB) {   // k cols: swizzled within head
          #pragma unroll
          for (int r = 0; r < 4; ++r) {
            const int row = row0 + r;
            qk[(size_t)row * LQK + (col & ~127) + ((col & 127) ^ ((row & 7) << 3))] =
                f2b(acc[ri][cj][r] + bvs);
          }
        } else {                        // v cols -> transposed+swizzled store into vt
          const int c2 = col - 2 * C_EMB;
          const int bb = row0 >> 11;
          const int t0v = row0 & (T_SEQ - 1);
          const int vrow = (bb * NH + (c2 >> 7)) * HD + (c2 & 127);
          ushort4 p;
          p.x = f2b(acc[ri][cj][0] + bvs); p.y = f2b(acc[ri][cj][1] + bvs);
          p.z = f2b(acc[ri][cj][2] + bvs); p.w = f2b(acc[ri][cj][3] + bvs);
          *(ushort4*)(vt + (size_t)vrow * T_SEQ + (t0v ^ ((vrow & 7) << 3))) = p;
        }
      }
    }
  }
}

// ---------------------------------------------------------------------------
// 128x256 2-phase-per-tile GEMM (r6 kernel, refcheck'd in composition).
// Used for the PROJ GEMM: grid (2048/256, 4096/128) = 8 x 32 = 256 blocks
// = EXACTLY 1 round at 1 block/CU (vs 512 x 128^2 m97 blocks at ~350 TF).
// r6 measured 3 rounds of 256 blocks in 136 µs -> ~45 µs for proj's 1 round.
//   LDS 96 KiB: dbuf x (A 128x64 + B 256x64) bf16, per-wave 64x64 out.
//   Stages: ph1 B(t1), ph2 A(ta)+VMC2, ph3 B(ta), ph4 A(tb)+VMC2.
//   Queue at VMC2(ph2): [A(t1)2, B(t1)4, A(ta)2] -> drains t1 (ph3 reads it).
//   Queue at VMC2(ph4): [A(ta)2, B(ta)4, A(tb)2] -> drains ta (next ph1).
// ---------------------------------------------------------------------------
#define STAGE_A6(t) do { \
    const unsigned short* g_ = Ag0 + (size_t)(t) * 64; \
    unsigned short* l_ = lds8 + ((t) & 1) * 8192 + tid * 8; \
    async_cp16(g_, l_); \
    async_cp16(g_ + (size_t)64 * lda, l_ + 4096); \
  } while (0)
#define STAGE_B6(t) do { \
    const unsigned short* g_ = Bg0 + (size_t)(t) * 64; \
    unsigned short* l_ = lds8 + 16384 + ((t) & 1) * 16384 + tid * 8; \
    async_cp16(g_, l_); \
    async_cp16(g_ + (size_t)64 * ldb,  l_ + 4096); \
    async_cp16(g_ + (size_t)128 * ldb, l_ + 8192); \
    async_cp16(g_ + (size_t)192 * ldb, l_ + 12288); \
  } while (0)

#define LOADA6(ab) do { \
    _Pragma("unroll") for (int rt_ = 0; rt_ < 4; ++rt_) { \
      af[rt_][0] = *(const bf16x8*)((ab) + rt_ * 1024 + kx0); \
      af[rt_][1] = *(const bf16x8*)((ab) + rt_ * 1024 + kx1); \
    } } while (0)
#define LOADB6(bb, cj0) do { \
    bv_[(cj0)][0]     = *(const bf16x8*)((bb) + (cj0) * 1024 + kx0); \
    bv_[(cj0)][1]     = *(const bf16x8*)((bb) + (cj0) * 1024 + kx1); \
    bv_[(cj0) + 1][0] = *(const bf16x8*)((bb) + ((cj0) + 1) * 1024 + kx0); \
    bv_[(cj0) + 1][1] = *(const bf16x8*)((bb) + ((cj0) + 1) * 1024 + kx1); \
  } while (0)
#define MFMAQ6(cq) do { \
    __builtin_amdgcn_s_setprio(1); \
    _Pragma("unroll") for (int rt_ = 0; rt_ < 4; ++rt_) \
      _Pragma("unroll") for (int ct_ = 0; ct_ < 2; ++ct_) \
        _Pragma("unroll") for (int kk_ = 0; kk_ < 2; ++kk_) \
          acc[rt_][(cq) * 2 + ct_] = __builtin_amdgcn_mfma_f32_16x16x32_bf16( \
              af[rt_][kk_], bv_[(cq) * 2 + ct_][kk_], acc[rt_][(cq) * 2 + ct_], 0, 0, 0); \
    __builtin_amdgcn_s_setprio(0); \
  } while (0)

template <int MODE, typename OutT>
__global__ __launch_bounds__(512, 1) void gemm6_bt(
    const unsigned short* __restrict__ A, int lda,
    const unsigned short* __restrict__ Bt, int ldb,
    const float* __restrict__ bias,
    OutT* __restrict__ C, int ldc,
    unsigned short* __restrict__ qk, unsigned short* __restrict__ vt, int K) {
  // [A buf0 8192 | A buf1 8192 | B buf0 16384 | B buf1 16384] shorts = 96 KiB
  __shared__ __align__(16) unsigned short lds8[49152];

  const int tid = threadIdx.x;
  const int wave = tid >> 6, lane = tid & 63;
  const int wm = wave >> 2, wn = wave & 3;
  const int ln = lane & 15, lq = lane >> 4;

  const int nbx = gridDim.x;
  int bid = blockIdx.y * nbx + blockIdx.x;
  const int nwg = nbx * gridDim.y;
  if (!(nwg & 7)) bid = (bid & 7) * (nwg >> 3) + (bid >> 3);   // XCD swizzle (bijective: nwg%8==0)
  const int bm0 = (bid / nbx) * 128;
  const int bn0 = (bid % nbx) * 256;

  // staging: thread covers rows (tid>>3)+{0,64,(128,192 for B)}, 16B slot
  // (tid&7); pre-swizzled global k-offset = (slot ^ (row&7))*8 shorts.
  const int srow = tid >> 3;
  const int scol = ((tid & 7) ^ (srow & 7)) << 3;
  const unsigned short* Ag0 = A  + (size_t)(bm0 + srow) * lda + scol;
  const unsigned short* Bg0 = Bt + (size_t)(bn0 + srow) * ldb + scol;

  // compute-side swizzled k-offsets (shorts): (ko + lq*8) ^ ((ln&7)<<3)
  const int kx0 = (lq * 8) ^ ((ln & 7) << 3);
  const int kx1 = (32 + lq * 8) ^ ((ln & 7) << 3);
  const unsigned short* Ab0 = lds8 + (wm * 64 + ln) * 64;
  const unsigned short* Ab1 = Ab0 + 8192;
  const unsigned short* Bb0 = lds8 + 16384 + (wn * 64 + ln) * 64;
  const unsigned short* Bb1 = Bb0 + 16384;

  f32x4 acc[4][4];
  #pragma unroll
  for (int i = 0; i < 4; ++i)
    #pragma unroll
    for (int j = 0; j < 4; ++j) acc[i][j] = (f32x4){0.f, 0.f, 0.f, 0.f};
  bf16x8 af[4][2], bv_[4][2];

  // prologue: A(0),B(0),A(1) (8 loads); VMC2 drains tile0, leaves A(1)x2.
  STAGE_A6(0); STAGE_B6(0); STAGE_A6(1);
  VMC2;
  BAR8;

  const int NT = K >> 6, NI = NT >> 1;
  for (int i = 0; i < NI; ++i) {
    const int t1 = 2 * i + 1;
    const int ta = (2 * i + 2 < NT) ? (2 * i + 2) : (2 * i);      // tail: restage (same bytes)
    const int tb = (2 * i + 3 < NT) ? (2 * i + 3) : (2 * i + 1);
    // ---- K-tile t0 (buf0): 2 phases
    LOADA6(Ab0); LOADB6(Bb0, 0); STAGE_B6(t1);        BAR8; MFMAQ6(0); BAR8;  // ph1
    LOADB6(Bb0, 2);              STAGE_A6(ta); VMC2;  BAR8; MFMAQ6(1); BAR8;  // ph2
    // ---- K-tile t1 (buf1): 2 phases
    LOADA6(Ab1); LOADB6(Bb1, 0); STAGE_B6(ta);        BAR8; MFMAQ6(0); BAR8;  // ph3
    LOADB6(Bb1, 2);              STAGE_A6(tb); VMC2;  BAR8; MFMAQ6(1); BAR8;  // ph4
  }

  gemm_epilogue<MODE, OutT>(acc, bias, C, ldc, qk, vt, bm0, bn0, wm, wn, ln, lq);
}

// ---------------------------------------------------------------------------
// Tier B GEMM fallback (validated round-2 structure).
// ---------------------------------------------------------------------------
template <int MODE, typename AT, typename OutT>
__global__ __launch_bounds__(256) void gemm_any(const AT* __restrict__ A, int lda,
                                                const float* __restrict__ B, int ldb,
                                                const float* __restrict__ bias,
                                                OutT* __restrict__ C, int ldc,
                                                unsigned short* __restrict__ qk,
                                                unsigned short* __restrict__ vt,
                                                int N, int K) {
  __shared__ __align__(16) unsigned short As[128 * 32];
  __shared__ __align__(16) unsigned short Bs[128 * 32];
  __shared__ __align__(16) float Bstage[32 * 132];

  const int tid = threadIdx.x;
  const int wave = tid >> 6, lane = tid & 63;
  const int wm = wave >> 1, wn = wave & 1;
  const int ln = lane & 15, lq = lane >> 4;
  const int bm0 = blockIdx.y * 128, bn0 = blockIdx.x * 128;

  f32x4 acc[4][4];
  #pragma unroll
  for (int i = 0; i < 4; ++i)
    #pragma unroll
    for (int j = 0; j < 4; ++j) acc[i][j] = (f32x4){0.f, 0.f, 0.f, 0.f};

  for (int k0 = 0; k0 < K; k0 += 32) {
    #pragma unroll
    for (int j = 0; j < 4; ++j) {
      const int item = tid + j * 256;
      const int m = item >> 3;
      const int kf = (item & 7) * 4;
      *(ushort4*)(As + m * 32 + kf) = load4_bf16(A + (size_t)(bm0 + m) * lda + k0 + kf);
    }
    #pragma unroll
    for (int j = 0; j < 4; ++j) {
      const int item = tid + j * 256;
      const int kr = item >> 5;
      const int nf = (item & 31) * 4;
      *(float4*)(Bstage + kr * 132 + nf) =
          *(const float4*)(B + (size_t)(k0 + kr) * ldb + bn0 + nf);
    }
    __syncthreads();
    #pragma unroll
    for (int j = 0; j < 4; ++j) {
      const int item = tid + j * 256;
      const int n = item >> 3;
      const int kq = item & 7;
      const int k = kq * 4;
      ushort4 h4;
      h4.x = f2b(Bstage[(k + 0) * 132 + n]);
      h4.y = f2b(Bstage[(k + 1) * 132 + n]);
      h4.z = f2b(Bstage[(k + 2) * 132 + n]);
      h4.w = f2b(Bstage[(k + 3) * 132 + n]);
      *(ushort4*)(Bs + n * 32 + (((kq >> 1) ^ (n & 3)) << 3) + ((kq & 1) << 2)) = h4;
    }
    __syncthreads();
    bf16x8 af[4], bfv[4];
    #pragma unroll
    for (int i = 0; i < 4; ++i) {
      af[i] = *(const bf16x8*)(As + (wm * 64 + i * 16 + ln) * 32 + lq * 8);
      const int n = wn * 64 + i * 16 + ln;
      bfv[i] = *(const bf16x8*)(Bs + n * 32 + ((lq ^ (n & 3)) << 3));
    }
    #pragma unroll
    for (int i = 0; i < 4; ++i)
      #pragma unroll
      for (int j = 0; j < 4; ++j)
        acc[i][j] = __builtin_amdgcn_mfma_f32_16x16x32_bf16(af[i], bfv[j], acc[i][j], 0, 0, 0);
    __syncthreads();
  }
  gemm_epilogue<MODE, OutT>(acc, bias, C, ldc, qk, vt, bm0, bn0, wm, wn, ln, lq);
}

// --------------------------------------------------------------- prep (fused)
static __device__ __forceinline__ void transpose_body(
    const float* __restrict__ in, unsigned short* __restrict__ out,
    int R, int Cc, int bx, int by, float (*t)[33]) {
  const int tx = threadIdx.x & 31, ty = threadIdx.x >> 5;
  #pragma unroll
  for (int j = 0; j < 32; j += 8)
    t[ty + j][tx] = in[(size_t)(by + ty + j) * Cc + bx + tx];
  __syncthreads();
  #pragma unroll
  for (int j = 0; j < 32; j += 8)
    out[(size_t)(bx + ty + j) * R + by + tx] = f2b(t[tx][ty + j]);
}

__global__ __launch_bounds__(256) void prep_all(
    const float* __restrict__ x, unsigned short* __restrict__ xb,
    const float* __restrict__ Wa, unsigned short* __restrict__ WaT,
    const float* __restrict__ Wp, unsigned short* __restrict__ WpT) {
  __shared__ float t[32][33];
  const int NCAST = (M_ROWS * C_EMB / 4) / 256;        // 8192
  const int NTA_X = N_QKV / 32;                        // 192
  const int NTA   = NTA_X * (C_EMB / 32);              // 12288
  const int NTP_X = C_EMB / 32;                        // 64
  const int bid = blockIdx.x;
  if (bid < NCAST) {
    const int i = bid * 256 + threadIdx.x;
    float4 v = ((const float4*)x)[i];
    ushort4 o; o.x = f2b(v.x); o.y = f2b(v.y); o.z = f2b(v.z); o.w = f2b(v.w);
    ((ushort4*)xb)[i] = o;
  } else if (bid < NCAST + NTA) {
    const int tb = bid - NCAST;
    transpose_body(Wa, WaT, C_EMB, N_QKV, (tb % NTA_X) * 32, (tb / NTA_X) * 32, t);
  } else {
    const int tb = bid - NCAST - NTA;
    transpose_body(Wp, WpT, C_EMB, C_EMB, (tb % NTP_X) * 32, (tb / NTP_X) * 32, t);
  }
}

// ---------------------------------------------------------------------------
// Flash attention (r5/r6 512-thread version — best measured).
// 8 waves x 16 q; double-buffered K/V via global_load_lds (swizzle baked
// into global layout); counted vmcnt(4) + raw s_barrier; setprio on MFMA.
// ---------------------------------------------------------------------------
__global__ __launch_bounds__(512, 4) void attn_st(unsigned short* __restrict__ qk,
                                                  const unsigned short* __restrict__ vt) {
  // 2 buffers x (K [64][128] + V^T [128][64]) = 2 x 16384 shorts = 64 KiB.
  // Epilogue reuses [0..17408) as Os[128][136].
  __shared__ __align__(16) unsigned short smem[32768];

  const int tid = threadIdx.x;
  const int w = tid >> 6, lane = tid & 63;
  const int ln = lane & 15, lq = lane >> 4;
  const int b = blockIdx.z, h = blockIdx.y;
  const int j = (b == 0) ? (15 - (int)blockIdx.x) : (int)blockIdx.x;
  const int qb0 = j * 128;
  const float EXPSC = 0.08838834764831845f * 1.4426950408889634f;
  const int xsw = (ln & 7) << 3;   // read-side XOR (row&7 == ln&7 for both K and V reads)

  // Q fragments (B-operand: n=ln=query, k=lq*8..) straight from global, once
  const int wq0 = qb0 + w * 16;
  const int qg = wq0 + ln;
  const unsigned short* Qp = qk + (size_t)(b * T_SEQ + qg) * LQK + h * HD + lq * 8;
  bf16x8 bq[4];
  #pragma unroll
  for (int ks = 0; ks < 4; ++ks) bq[ks] = *(const bf16x8*)(Qp + ks * 32);

  // staging bases (global layouts pre-swizzled -> linear row copies)
  const unsigned short* Kg = qk + (size_t)(b * T_SEQ) * LQK + C_EMB + h * HD;
  const unsigned short* Vg = vt + ((size_t)(b * NH + h) * HD) * T_SEQ;
  const int krow = tid >> 4, kc16 = (tid & 15) * 8;   // K: 32 rows/chunk x 16 slots
  const int vrow = tid >> 3, vc16 = (tid & 7) * 8;    // V: 64 rows/chunk x 8 slots

  f32x4 ot[8];  // O^T accum: regs = d = dt*16+lq*4+r, col = query ln
  #pragma unroll
  for (int dt = 0; dt < 8; ++dt) ot[dt] = (f32x4){0.f, 0.f, 0.f, 0.f};
  float l_i = 0.f;

  // prologue: stage tiles 0 (buf0) and 1 (buf1): 4 cp16/thread each
  {
    unsigned short* b0 = smem;
    async_cp16(Kg + (size_t)(0 * 64 + krow) * LQK + kc16,        b0 + tid * 8);
    async_cp16(Kg + (size_t)(0 * 64 + krow + 32) * LQK + kc16,   b0 + 4096 + tid * 8);
    async_cp16(Vg + (size_t)vrow * T_SEQ + 0 * 64 + vc16,        b0 + 8192 + tid * 8);
    async_cp16(Vg + (size_t)(vrow + 64) * T_SEQ + 0 * 64 + vc16, b0 + 12288 + tid * 8);
    unsigned short* b1 = smem + 16384;
    async_cp16(Kg + (size_t)(1 * 64 + krow) * LQK + kc16,        b1 + tid * 8);
    async_cp16(Kg + (size_t)(1 * 64 + krow + 32) * LQK + kc16,   b1 + 4096 + tid * 8);
    async_cp16(Vg + (size_t)vrow * T_SEQ + 1 * 64 + vc16,        b1 + 8192 + tid * 8);
    async_cp16(Vg + (size_t)(vrow + 64) * T_SEQ + 1 * 64 + vc16, b1 + 12288 + tid * 8);
  }

  const int kbmax = 2 * j + 1;
  for (int kb = 0; kb <= kbmax; ++kb) {
    asm volatile("s_waitcnt vmcnt(4)" ::: "memory");  // tile kb landed (tile kb+1 in flight)
    __builtin_amdgcn_s_barrier();
    const unsigned short* Ksb = smem + (kb & 1) * 16384;
    const unsigned short* Vsb = Ksb + 8192;

    if (kb * 64 <= wq0 + 15) {            // wave has unmasked work this block
      const bool diag = (kb * 64 + 63 > wq0);

      // ---- S^T = K Q^T
      f32x4 st[4];
      __builtin_amdgcn_s_setprio(1);
      #pragma unroll
      for (int kt = 0; kt < 4; ++kt) {
        st[kt] = (f32x4){0.f, 0.f, 0.f, 0.f};
        #pragma unroll
        for (int ks = 0; ks < 4; ++ks) {
          bf16x8 ak = *(const bf16x8*)(Ksb + (kt * 16 + ln) * 128 + ((ks * 32 + lq * 8) ^ xsw));
          st[kt] = __builtin_amdgcn_mfma_f32_16x16x32_bf16(ak, bq[ks], st[kt], 0, 0, 0);
        }
      }
      __builtin_amdgcn_s_setprio(0);

      // ---- max-free softmax: p = exp2(s*EXPSC); zero masked; accumulate l
      short4v pf[4];
      #pragma unroll
      for (int kt = 0; kt < 4; ++kt)
        #pragma unroll
        for (int r = 0; r < 4; ++r) {
          float p = __builtin_exp2f(st[kt][r] * EXPSC);
          if (diag && (kb * 64 + kt * 16 + lq * 4 + r > qg)) p = 0.f;
          l_i += p;
          pf[kt][r] = (short)f2b(p);
        }

      // ---- O^T += V^T P^T : K=16 MFMA, P straight from registers
      __builtin_amdgcn_s_setprio(1);
      #pragma unroll
      for (int kt = 0; kt < 4; ++kt)
        #pragma unroll
        for (int dt = 0; dt < 8; ++dt) {
          short4v av = *(const short4v*)(Vsb + (dt * 16 + ln) * 64 + ((kt * 16 + lq * 4) ^ xsw));
          ot[dt] = __builtin_amdgcn_mfma_f32_16x16x16bf16_1k(av, pf[kt], ot[dt], 0, 0, 0);
        }
      __builtin_amdgcn_s_setprio(0);
    }

    __builtin_amdgcn_s_barrier();        // all waves done reading buf[kb&1]
    const int kn = (kb + 2 <= kbmax) ? (kb + 2) : kbmax;  // clamp keeps queue depth
    unsigned short* dst = smem + (kb & 1) * 16384;
    async_cp16(Kg + (size_t)(kn * 64 + krow) * LQK + kc16,        dst + tid * 8);
    async_cp16(Kg + (size_t)(kn * 64 + krow + 32) * LQK + kc16,   dst + 4096 + tid * 8);
    async_cp16(Vg + (size_t)vrow * T_SEQ + kn * 64 + vc16,        dst + 8192 + tid * 8);
    async_cp16(Vg + (size_t)(vrow + 64) * T_SEQ + kn * 64 + vc16, dst + 12288 + tid * 8);
  }

  // ---- final l reduction across the 4 partner lanes (once)
  l_i += __shfl_xor(l_i, 16);
  l_i += __shfl_xor(l_i, 32);
  const float inv = 1.f / l_i;

  // ---- epilogue: O^T -> O via LDS (smem as Os[128][136]), coalesced store.
  // Drain in-flight staging before reusing smem.
  asm volatile("s_waitcnt vmcnt(0)" ::: "memory");
  __syncthreads();
  #pragma unroll
  for (int dt = 0; dt < 8; ++dt) {
    ushort4 p4;
    p4.x = f2b(ot[dt][0] * inv); p4.y = f2b(ot[dt][1] * inv);
    p4.z = f2b(ot[dt][2] * inv); p4.w = f2b(ot[dt][3] * inv);
    *(ushort4*)(smem + (w * 16 + ln) * 136 + dt * 16 + lq * 4) = p4;
  }
  __syncthreads();
  #pragma unroll
  for (int jj = 0; jj < 4; ++jj) {        // 128 rows x 16 uint4 = 2048 items
    const int s = tid + jj * 512;
    const int row = s >> 4, c8 = s & 15;
    *(uint4*)(qk + (size_t)(b * T_SEQ + qb0 + row) * LQK + h * HD + c8 * 8) =
        *(const uint4*)(smem + row * 136 + c8 * 8);
  }
}

// ---------------------------------------------------------------- launch
extern "C" void kernel_launch(void* const* d_in, const int* in_sizes, int n_in,
                              void* d_out, int out_size, void* d_ws, size_t ws_size,
                              hipStream_t stream) {
  (void)in_sizes; (void)n_in; (void)out_size;
  const float* x      = (const float*)d_in[0];
  const float* W_attn = (const float*)d_in[1];
  const float* b_attn = (const float*)d_in[2];
  const float* W_proj = (const float*)d_in[3];
  const float* b_proj = (const float*)d_in[4];
  float* out = (float*)d_out;

  char* ws = (char*)d_ws;
  unsigned short* qk = (unsigned short*)(ws);                  // 32 MiB [4096][4096]
  unsigned short* vt = (unsigned short*)(ws + 33554432);       // 16 MiB [B*NH*HD][T]
  unsigned short* xb  = (unsigned short*)(ws + 50331648);      // 16 MiB x bf16
  unsigned short* WaT = (unsigned short*)(ws + 67108864);      // 24 MiB W_attn^T bf16
  unsigned short* WpT = (unsigned short*)(ws + 92274688);      // 8  MiB W_proj^T bf16
  const bool tierA = (ws_size >= 100663296);                   // 96 MiB

  if (tierA) {
    const int NPREP = 8192 + 12288 + 4096;   // cast + W_attn^T + W_proj^T
    prep_all<<<NPREP, 256, 0, stream>>>(x, xb, W_attn, WaT, W_proj, WpT);
    gemm8_bt<1, unsigned short><<<dim3(N_QKV / 256, M_ROWS / 256), 512, 0, stream>>>(
        xb, C_EMB, WaT, C_EMB, b_attn, (unsigned short*)nullptr, 0, qk, vt, C_EMB);
  } else {
    gemm_any<1, float, unsigned short><<<dim3(N_QKV / 128, M_ROWS / 128), 256, 0, stream>>>(
        x, C_EMB, W_attn, N_QKV, b_attn, (unsigned short*)nullptr, 0, qk, vt, N_QKV, C_EMB);
  }

  attn_st<<<dim3(16, NH, B_SZ), 512, 0, stream>>>(qk, vt);

  if (tierA) {
    gemm6_bt<0, float><<<dim3(C_EMB / 256, M_ROWS / 128), 512, 0, stream>>>(
        qk, LQK, WpT, C_EMB, b_proj, out, C_EMB, nullptr, nullptr, C_EMB);
  } else {
    gemm_any<0, unsigned short, float><<<dim3(C_EMB / 128, M_ROWS / 128), 256, 0, stream>>>(
        qk, LQK, W_proj, C_EMB, b_proj, out, C_EMB, nullptr, nullptr, C_EMB, C_EMB);
  }
}